// Round 12
// baseline (439.463 us; speedup 1.0000x reference)
//
#include <hip/hip_runtime.h>
#include <math.h>

constexpr int NPTS  = 8192;
constexpr int HIDC  = 128;
constexpr int OUTC2 = 256;
constexpr int PQC   = 512;
constexpr int KK1   = 16;
constexpr int KK2   = 8;

typedef __attribute__((ext_vector_type(8))) short short8;
typedef __attribute__((ext_vector_type(4))) float f32x4;

__device__ __forceinline__ f32x4 mfma16(short8 a, short8 b, f32x4 c) {
  return __builtin_amdgcn_mfma_f32_16x16x32_bf16(a, b, c, 0, 0, 0);
}

__device__ __forceinline__ void async_ld16(void* lds, const void* g) {
  __builtin_amdgcn_global_load_lds(
      (const __attribute__((address_space(1))) unsigned int*)g,
      (__attribute__((address_space(3))) unsigned int*)lds, 16, 0, 0);
}

// packed-key insert: keys unique (j embedded) -> strict < is exact lex.
template <int K>
__device__ __forceinline__ void ins_u(unsigned (&kk)[K], unsigned v) {
  if (v < kk[K - 1]) {
    kk[K - 1] = v;
    #pragma unroll
    for (int p = K - 1; p > 0; --p) {
      unsigned a = kk[p - 1], b = kk[p];
      kk[p - 1] = a < b ? a : b;
      kk[p]     = a < b ? b : a;
    }
  }
}

// lexicographic (d, idx) insert — exact fp32 merging.
template <int K>
__device__ __forceinline__ void ins_lex(float (&kf)[K], int (&ki)[K], float v, int j) {
  bool ins = (v < kf[K - 1]) || (v == kf[K - 1] && j < ki[K - 1]);
  if (ins) {
    kf[K - 1] = v; ki[K - 1] = j;
    #pragma unroll
    for (int p = K - 1; p > 0; --p) {
      float fa = kf[p - 1], fb = kf[p];
      int   ia = ki[p - 1], ib = ki[p];
      bool sw = (fb < fa) || (fb == fa && ib < ia);
      kf[p - 1] = sw ? fb : fa; ki[p - 1] = sw ? ib : ia;
      kf[p]     = sw ? fa : fb; ki[p]     = sw ? ia : ib;
    }
  }
}

__device__ __forceinline__ unsigned short bf16_rn(float x) {
  unsigned int u = __float_as_uint(x);
  unsigned int r = u + 0x7fffu + ((u >> 16) & 1u);
  return (unsigned short)(r >> 16);
}

// ---------------------------------------------------------------- pack x
__global__ void pack_x_kernel(const float* __restrict__ x, float4* __restrict__ x4) {
  int i = blockIdx.x * blockDim.x + threadIdx.x;
  if (i < NPTS) {
    float a = x[3 * i], b = x[3 * i + 1], c = x[3 * i + 2];
    x4[i] = make_float4(a, b, c, a * a + b * b + c * c);
  }
}

// ---------------------------------------------------------------- Wc = [Wl-Wh | Wh] for layer2 stage1
__global__ void prep_w1_kernel(const float* __restrict__ W1, float* __restrict__ Wc) {
  int idx = blockIdx.x * 256 + threadIdx.x;    // 128*512
  int k = idx >> 9, c = idx & 511;
  float wh = W1[(size_t)(HIDC + k) * OUTC2 + (c & 255)];
  Wc[idx] = (c < OUTC2) ? (W1[(size_t)k * OUTC2 + c] - wh) : wh;
}

// ---------------------------------------------------------------- W2^T bf16 hi/lo for ec2 MFMA B-frags
__global__ void prep_w2_kernel(const float* __restrict__ W2,
                               unsigned short* __restrict__ W2Thi,
                               unsigned short* __restrict__ W2Tlo) {
  const int c = blockIdx.x;      // out channel (row of W2T)
  const int k = threadIdx.x;     // inner dim
  float w = W2[(size_t)k * OUTC2 + c];
  unsigned short hi = bf16_rn(w);
  float fh = __uint_as_float(((unsigned int)hi) << 16);
  unsigned short lo = bf16_rn(w - fh);
  W2Thi[(size_t)c * OUTC2 + k] = hi;
  W2Tlo[(size_t)c * OUTC2 + k] = lo;
}

// ---------------------------------------------------------------- KNN1 (C=3, K=16) — unchanged (R11-validated)
__global__ __launch_bounds__(256) void knn3_kernel(const float4* __restrict__ X4,
                                                   int* __restrict__ idx_out) {
  const int tid  = threadIdx.x;
  const int lane = tid & 63;
  const int wv   = __builtin_amdgcn_readfirstlane(tid >> 6);
  const int q    = blockIdx.x * 4 + wv;

  const float4 qv = X4[q];

  unsigned kk[KK2];
  #pragma unroll
  for (int k = 0; k < KK2; ++k) kk[k] = 0xFFFFFFFFu;

  for (int c = 0; c < NPTS / 64; ++c) {
    const int j = c * 64 + lane;
    float4 pj = X4[j];
    float d = fmaxf(qv.w + pj.w - 2.f * (qv.x * pj.x + qv.y * pj.y + qv.z * pj.z), 0.f);
    unsigned key = (__float_as_uint(d) & 0xFFFFE000u) | (unsigned)j;
    if (j == q) key = 0xFFFFFFFFu;
    ins_u<KK2>(kk, key);
  }

  float kf[KK2]; int kj[KK2];
  #pragma unroll
  for (int k = 0; k < KK2; ++k) { kf[k] = INFINITY; kj[k] = 0x7fffffff; }
  #pragma unroll
  for (int k = 0; k < KK2; ++k) {
    int j = (int)(kk[k] & 0x1FFFu);
    float4 pj = X4[j];
    float d = qv.w + pj.w - 2.f * (qv.x * pj.x + qv.y * pj.y + qv.z * pj.z);
    if (kk[k] == 0xFFFFFFFFu) { d = INFINITY; j = 0x7fffffff; }
    ins_lex<KK2>(kf, kj, d, j);
  }

  #pragma unroll
  for (int k = 0; k < KK1; ++k) {
    float mf = kf[0]; int mj = kj[0];
    #pragma unroll
    for (int m = 1; m <= 32; m <<= 1) {
      float of = __shfl_xor(mf, m, 64);
      int   oj = __shfl_xor(mj, m, 64);
      bool g = (of < mf) || (of == mf && oj < mj);
      mf = g ? of : mf; mj = g ? oj : mj;
    }
    const bool won = (kf[0] == mf) && (kj[0] == mj);
    if (won) {
      idx_out[(size_t)q * KK1 + k] = mj;
      #pragma unroll
      for (int p = 0; p < KK2 - 1; ++p) { kf[p] = kf[p + 1]; kj[p] = kj[p + 1]; }
      kf[KK2 - 1] = INFINITY; kj[KK2 - 1] = 0x7fffffff;
    }
  }
}

// ---------------------------------------------------------------- EdgeConv 1 (unchanged)
__global__ __launch_bounds__(256) void edgeconv1_kernel(
    const float* __restrict__ X, const int* __restrict__ knn,
    const float* __restrict__ W1, const float* __restrict__ b1,
    const float* __restrict__ W2, const float* __restrict__ b2,
    float* __restrict__ H, unsigned short* __restrict__ Hhi,
    unsigned short* __restrict__ Hlo, float* __restrict__ SQ2) {
  __shared__ float h1[8][KK1][HIDC];
  __shared__ float xjs[8][KK1][3];
  __shared__ float xis[8][3];
  const int tid  = threadIdx.x;
  const int lane = tid & 63;
  const int wv   = __builtin_amdgcn_readfirstlane(tid >> 6);
  const int half = lane >> 5;
  const int hl   = lane & 31;
  const int lp   = wv * 2 + half;
  const int p    = blockIdx.x * 8 + lp;
  const int ch0  = hl * 4;

  if (hl < KK1) {
    int j = knn[p * KK1 + hl];
    xjs[lp][hl][0] = X[3 * j]; xjs[lp][hl][1] = X[3 * j + 1]; xjs[lp][hl][2] = X[3 * j + 2];
  } else if (hl < KK1 + 3) {
    xis[lp][hl - KK1] = X[3 * p + hl - KK1];
  }
  __syncthreads();

  f32x4 w1r[6];
  #pragma unroll
  for (int c = 0; c < 6; ++c) w1r[c] = *(const f32x4*)&W1[c * HIDC + ch0];
  f32x4 b1v = *(const f32x4*)&b1[ch0];
  const float xi0 = xis[lp][0], xi1 = xis[lp][1], xi2 = xis[lp][2];
  f32x4 base;
  #pragma unroll
  for (int c = 0; c < 4; ++c)
    base[c] = b1v[c] + xi0 * w1r[0][c] + xi1 * w1r[1][c] + xi2 * w1r[2][c];
  #pragma unroll
  for (int e = 0; e < KK1; ++e) {
    float dx = xjs[lp][e][0] - xi0, dy = xjs[lp][e][1] - xi1, dz = xjs[lp][e][2] - xi2;
    f32x4 v;
    #pragma unroll
    for (int c = 0; c < 4; ++c)
      v[c] = fmaxf(base[c] + dx * w1r[3][c] + dy * w1r[4][c] + dz * w1r[5][c], 0.f);
    *(f32x4*)&h1[lp][e][ch0] = v;
  }
  __syncthreads();

  float acc[KK1][4];
  #pragma unroll
  for (int e = 0; e < KK1; ++e)
    #pragma unroll
    for (int c = 0; c < 4; ++c) acc[e][c] = 0.f;
  for (int c4 = 0; c4 < HIDC / 4; ++c4) {
    f32x4 w2r[4];
    #pragma unroll
    for (int cc = 0; cc < 4; ++cc)
      w2r[cc] = *(const f32x4*)&W2[(c4 * 4 + cc) * HIDC + ch0];
    #pragma unroll
    for (int e = 0; e < KK1; ++e) {
      f32x4 hv = *(const f32x4*)&h1[lp][e][c4 * 4];
      #pragma unroll
      for (int cc = 0; cc < 4; ++cc)
        #pragma unroll
        for (int c = 0; c < 4; ++c) acc[e][c] += hv[cc] * w2r[cc][c];
    }
  }
  f32x4 b2v = *(const f32x4*)&b2[ch0];
  f32x4 outv;
  #pragma unroll
  for (int c = 0; c < 4; ++c) {
    float m = -INFINITY;
    #pragma unroll
    for (int e = 0; e < KK1; ++e) m = fmaxf(m, acc[e][c]);
    outv[c] = m + b2v[c];
  }
  *(f32x4*)&H[(size_t)p * HIDC + ch0] = outv;

  unsigned short hb[4], lb[4];
  #pragma unroll
  for (int c = 0; c < 4; ++c) {
    hb[c] = bf16_rn(outv[c]);
    float fh = __uint_as_float(((unsigned int)hb[c]) << 16);
    lb[c] = bf16_rn(outv[c] - fh);
  }
  *(ushort4*)&Hhi[(size_t)p * HIDC + ch0] = make_ushort4(hb[0], hb[1], hb[2], hb[3]);
  *(ushort4*)&Hlo[(size_t)p * HIDC + ch0] = make_ushort4(lb[0], lb[1], lb[2], lb[3]);

  float s = outv[0]*outv[0] + outv[1]*outv[1] + outv[2]*outv[2] + outv[3]*outv[3];
  #pragma unroll
  for (int m = 1; m <= 16; m <<= 1) s += __shfl_xor(s, m, 64);
  if (hl == 0) SQ2[p] = s;
}

// ---------------------------------------------------------------- PQ = H @ Wc (+b1 on P half)
__global__ __launch_bounds__(256) void gemm_pq_kernel(
    const float* __restrict__ H, const float* __restrict__ Wc,
    const float* __restrict__ b1, float* __restrict__ PQ) {
  __shared__ float Hs[32][HIDC];
  const int tid = threadIdx.x;
  const int rb  = blockIdx.x >> 3;
  const int cb  = blockIdx.x & 7;
  const int col = cb * 64 + (tid & 63);
  const int rg  = tid >> 6;

  #pragma unroll
  for (int u = 0; u < 4; ++u) {
    int idx = u * 256 + tid;
    int r = idx >> 5, k4 = idx & 31;
    *(f32x4*)&Hs[r][k4 * 4] = *(const f32x4*)&H[(size_t)(rb * 32 + r) * HIDC + k4 * 4];
  }
  __syncthreads();

  float acc[8] = {};
  for (int k = 0; k < HIDC; ++k) {
    float w = Wc[(size_t)k * PQC + col];
    #pragma unroll
    for (int i = 0; i < 8; ++i) acc[i] += Hs[rg * 8 + i][k] * w;
  }
  const float bb = (col < OUTC2) ? b1[col] : 0.f;
  #pragma unroll
  for (int i = 0; i < 8; ++i)
    PQ[(size_t)(rb * 32 + rg * 8 + i) * PQC + col] = acc[i] + bb;
}

// ---------------------------------------------------------------- KNN2 filter (unchanged from R10)
constexpr int JSPLIT = 16;
constexpr int JPB2   = NPTS / JSPLIT;
constexpr int NCH    = JPB2 / 16;
constexpr int CPQ    = JSPLIT * KK2;

__global__ __launch_bounds__(256) void knn128_filter_kernel(
    const unsigned short* __restrict__ Hhi, const unsigned short* __restrict__ Hlo,
    const float* __restrict__ SQ, int* __restrict__ pi2) {
  __shared__ __align__(16) unsigned short As[2][2][16 * HIDC];
  const int tid  = threadIdx.x;
  const int lane = tid & 63;
  const int wv   = __builtin_amdgcn_readfirstlane(tid >> 6);
  const int qb   = blockIdx.x >> 4;
  const int js   = blockIdx.x & 15;
  const int col  = lane & 15;
  const int kg   = lane >> 4;
  const int qg   = qb * 64 + wv * 16 + col;

  short8 qhi[4], qlo[4];
  #pragma unroll
  for (int s = 0; s < 4; ++s) {
    const size_t o = (size_t)qg * HIDC + s * 32 + kg * 8;
    qhi[s] = *reinterpret_cast<const short8*>(Hhi + o);
    qlo[s] = *reinterpret_cast<const short8*>(Hlo + o);
  }
  const float sqq = SQ[qg];

  unsigned kk[KK2];
  #pragma unroll
  for (int k = 0; k < KK2; ++k) kk[k] = 0xFFFFFFFFu;

  const int jbase = js * JPB2;

  const int srow = 4 * wv + (lane >> 4);
  const int sslt = (lane & 15) ^ (srow & 7);
  auto stage = [&](int buf, int ch) {
    const size_t gofs = (size_t)(jbase + ch * 16 + srow) * HIDC + sslt * 8;
    async_ld16((char*)&As[buf][0][0] + wv * 1024, Hhi + gofs);
    async_ld16((char*)&As[buf][1][0] + wv * 1024, Hlo + gofs);
  };

  stage(0, 0);
  asm volatile("s_waitcnt vmcnt(0)" ::: "memory");
  __syncthreads();

  for (int ch = 0; ch < NCH; ++ch) {
    const int cur = ch & 1;
    if (ch + 1 < NCH) stage(cur ^ 1, ch + 1);

    const int jb = jbase + ch * 16;
    short8 ahi[4], alo[4];
    const int rowb = col * 256;
    #pragma unroll
    for (int s = 0; s < 4; ++s) {
      const int sl = ((s * 4 + kg) ^ (col & 7)) * 16;
      ahi[s] = *(const short8*)((const char*)&As[cur][0][0] + rowb + sl);
      alo[s] = *(const short8*)((const char*)&As[cur][1][0] + rowb + sl);
    }
    f32x4 sqjv = *reinterpret_cast<const f32x4*>(SQ + jb + kg * 4);

    f32x4 acc = {0.f, 0.f, 0.f, 0.f};
    #pragma unroll
    for (int s = 0; s < 4; ++s) {
      acc = mfma16(ahi[s], qhi[s], acc);
      acc = mfma16(ahi[s], qlo[s], acc);
      acc = mfma16(alo[s], qhi[s], acc);
    }
    #pragma unroll
    for (int r = 0; r < 4; ++r) {
      const int jg = jb + kg * 4 + r;
      float d = fmaxf(sqq + sqjv[r] - 2.f * acc[r], 0.f);
      unsigned key = (__float_as_uint(d) & 0xFFFFE000u) | (unsigned)jg;
      if (jg == qg) key = 0xFFFFFFFFu;
      ins_u<KK2>(kk, key);
    }
    asm volatile("s_waitcnt vmcnt(0)" ::: "memory");
    __syncthreads();
  }

  #pragma unroll
  for (int dlt = 16; dlt <= 32; dlt <<= 1) {
    unsigned ok[KK2];
    #pragma unroll
    for (int k = 0; k < KK2; ++k) ok[k] = __shfl_xor((int)kk[k], dlt, 64);
    #pragma unroll
    for (int k = 0; k < KK2; ++k) ins_u<KK2>(kk, ok[k]);
  }
  if (lane < 16) {
    const size_t base = (size_t)qg * CPQ + js * KK2;
    #pragma unroll
    for (int k = 0; k < KK2; ++k) pi2[base + k] = (int)(kk[k] & 0x1FFFu);
  }
}

// ---------------------------------------------------------------- exact fp32 rescore (unchanged)
__global__ __launch_bounds__(256) void knn_rescore_kernel(
    const float* __restrict__ H, const float* __restrict__ SQ,
    const int* __restrict__ pi2, int* __restrict__ idx_out) {
  __shared__ float qrow[4][HIDC];
  const int tid  = threadIdx.x;
  const int wv   = tid >> 6;
  const int lane = tid & 63;
  const int q0   = blockIdx.x * 4;
  const int q    = q0 + wv;
  for (int u = tid; u < 4 * HIDC; u += 256)
    qrow[u >> 7][u & 127] = H[(size_t)(q0 + (u >> 7)) * HIDC + (u & 127)];
  __syncthreads();

  const int c0 = pi2[(size_t)q * CPQ + lane];
  const int c1 = pi2[(size_t)q * CPQ + 64 + lane];
  const float sqq = SQ[q];

  float dot0 = 0.f;
  {
    const float* crow = H + (size_t)c0 * HIDC;
    #pragma unroll 8
    for (int c4 = 0; c4 < HIDC / 4; ++c4) {
      f32x4 qv = *(const f32x4*)&qrow[wv][c4 * 4];
      f32x4 cv = *(const f32x4*)(crow + c4 * 4);
      dot0 += qv[0] * cv[0] + qv[1] * cv[1] + qv[2] * cv[2] + qv[3] * cv[3];
    }
  }
  float d0 = sqq + SQ[c0] - 2.f * dot0;

  float dot1 = 0.f;
  {
    const float* crow = H + (size_t)c1 * HIDC;
    #pragma unroll 8
    for (int c4 = 0; c4 < HIDC / 4; ++c4) {
      f32x4 qv = *(const f32x4*)&qrow[wv][c4 * 4];
      f32x4 cv = *(const f32x4*)(crow + c4 * 4);
      dot1 += qv[0] * cv[0] + qv[1] * cv[1] + qv[2] * cv[2] + qv[3] * cv[3];
    }
  }
  float d1 = sqq + SQ[c1] - 2.f * dot1;

  float kf[KK2]; int ki[KK2];
  kf[0] = d0; ki[0] = c0;
  #pragma unroll
  for (int k = 1; k < KK2; ++k) { kf[k] = INFINITY; ki[k] = 0x7fffffff; }
  ins_lex<KK2>(kf, ki, d1, c1);
  #pragma unroll
  for (int dlt = 1; dlt <= 32; dlt <<= 1) {
    float of[KK2]; int oi[KK2];
    #pragma unroll
    for (int k = 0; k < KK2; ++k) { of[k] = __shfl_xor(kf[k], dlt, 64); oi[k] = __shfl_xor(ki[k], dlt, 64); }
    #pragma unroll
    for (int k = 0; k < KK2; ++k) ins_lex<KK2>(kf, ki, of[k], oi[k]);
  }
  if (lane == 0) {
    #pragma unroll
    for (int k = 0; k < KK2; ++k) idx_out[(size_t)q * KK2 + k] = ki[k];
  }
}

// ---------------------------------------------------------------- EdgeConv 2 — MFMA stage-2
// Block = 4 points = 32 G-rows (8 edges each). Stage 1: wave wv computes
// g1 = relu(P[p]+Q[j]) for point p_base+wv, bf16 hi/lo into XOR-swizzled LDS
// (reg-staged: both write and read swizzled — rule-21 safe).
// Stage 2: D(32x256) = G @ W2 via 16x16x32 bf16 MFMA, 3 cross-terms
// (hh/hl/lh — same validated pattern as the filter). Wave owns M-tile
// (wv&1) x 8 N-tiles (wv>>1). B-frags = contiguous short8 from L2-resident
// W2T hi/lo. Epilogue: max over 4 acc rows + shfl_xor(16) -> per-point max.
__global__ __launch_bounds__(256) void edgeconv2_kernel(
    const float* __restrict__ PQ, const int* __restrict__ knn,
    const unsigned short* __restrict__ W2Thi, const unsigned short* __restrict__ W2Tlo,
    const float* __restrict__ b2, float* __restrict__ Out) {
  __shared__ __align__(16) unsigned short Ghi[32 * OUTC2];  // 16 KB
  __shared__ __align__(16) unsigned short Glo[32 * OUTC2];  // 16 KB
  const int tid  = threadIdx.x;
  const int lane = tid & 63;
  const int wv   = __builtin_amdgcn_readfirstlane(tid >> 6);
  const int p_base = blockIdx.x * 4;

  // ---- stage 1: g1 for point p_base+wv (wave-per-point)
  {
    const int p   = p_base + wv;
    const int ch0 = lane * 4;
    f32x4 pv = *(const f32x4*)&PQ[(size_t)p * PQC + ch0];
    #pragma unroll
    for (int e = 0; e < KK2; ++e) {
      const int j = knn[p * KK2 + e];
      f32x4 qv = *(const f32x4*)&PQ[(size_t)j * PQC + OUTC2 + ch0];
      unsigned short hb[4], lb[4];
      #pragma unroll
      for (int c = 0; c < 4; ++c) {
        float g = fmaxf(pv[c] + qv[c], 0.f);
        hb[c] = bf16_rn(g);
        float fh = __uint_as_float(((unsigned int)hb[c]) << 16);
        lb[c] = bf16_rn(g - fh);
      }
      const int r   = wv * 8 + e;                                // G row 0..31
      const int off = r * 512 + (((ch0 >> 3) ^ (r & 7)) << 4) + ((ch0 & 7) << 1);
      *(ushort4*)((char*)Ghi + off) = make_ushort4(hb[0], hb[1], hb[2], hb[3]);
      *(ushort4*)((char*)Glo + off) = make_ushort4(lb[0], lb[1], lb[2], lb[3]);
    }
  }
  __syncthreads();

  // ---- stage 2: MFMA GEMM. wave: M-tile mt = wv&1, N-tiles nh*8 .. +8
  const int col = lane & 15;
  const int kg  = lane >> 4;
  const int mt  = wv & 1;
  const int nh  = wv >> 1;
  const int ar  = mt * 16 + col;            // G row this lane's A-frag covers
  const int abase = ar * 512;

  f32x4 acc[8];
  #pragma unroll
  for (int n = 0; n < 8; ++n) acc[n] = (f32x4){0.f, 0.f, 0.f, 0.f};

  for (int s = 0; s < 8; ++s) {             // K-steps of 32
    const int asl = (((s * 4 + kg) ^ (ar & 7)) << 4);
    short8 ghi = *(const short8*)((const char*)Ghi + abase + asl);
    short8 glo = *(const short8*)((const char*)Glo + abase + asl);
    #pragma unroll
    for (int n = 0; n < 8; ++n) {
      const int bc = nh * 128 + n * 16 + col;      // out-channel column
      const size_t boff = (size_t)bc * OUTC2 + s * 32 + kg * 8;
      short8 bhi = *(const short8*)(W2Thi + boff);
      short8 blo = *(const short8*)(W2Tlo + boff);
      acc[n] = mfma16(ghi, bhi, acc[n]);
      acc[n] = mfma16(ghi, blo, acc[n]);
      acc[n] = mfma16(glo, bhi, acc[n]);
    }
  }

  // ---- epilogue: D row = kg*4+reg (edge), col = n*16+col (channel)
  // kg 0/1 -> point mt*2, kg 2/3 -> point mt*2+1. max over 4 regs, then ^16.
  const int pt = p_base + mt * 2 + (kg >> 1);
  #pragma unroll
  for (int n = 0; n < 8; ++n) {
    float m = fmaxf(fmaxf(acc[n][0], acc[n][1]), fmaxf(acc[n][2], acc[n][3]));
    m = fmaxf(m, __shfl_xor(m, 16, 64));
    if ((kg & 1) == 0) {
      const int ncol = nh * 128 + n * 16 + col;
      Out[(size_t)pt * OUTC2 + ncol] = m + b2[ncol];
    }
  }
}

// ---------------------------------------------------------------- launch
extern "C" void kernel_launch(void* const* d_in, const int* in_sizes, int n_in,
                              void* d_out, int out_size, void* d_ws, size_t ws_size,
                              hipStream_t stream) {
  const float* x   = (const float*)d_in[0];
  const float* W1a = (const float*)d_in[1];
  const float* b1a = (const float*)d_in[2];
  const float* W1b = (const float*)d_in[3];
  const float* b1b = (const float*)d_in[4];
  const float* W2a = (const float*)d_in[5];
  const float* b2a = (const float*)d_in[6];
  const float* W2b = (const float*)d_in[7];
  const float* b2b = (const float*)d_in[8];
  float* out = (float*)d_out;

  float* h    = (float*)d_ws;                       // 4 MB
  float* sq2  = h + (size_t)NPTS * HIDC;
  int*   idx1 = (int*)(sq2 + NPTS);
  int*   idx2 = idx1 + (size_t)NPTS * KK1;
  unsigned short* Hhi = (unsigned short*)(idx2 + (size_t)NPTS * KK2);  // 2 MB
  unsigned short* Hlo = Hhi + (size_t)NPTS * HIDC;                     // 2 MB
  int*   pi2  = (int*)(Hlo + (size_t)NPTS * HIDC);  // 4 MB
  float* Wc   = (float*)(pi2 + (size_t)NPTS * CPQ); // 256 KB
  float* PQ   = Wc + (size_t)HIDC * PQC;            // 16 MB
  unsigned short* W2Thi = (unsigned short*)(PQ + (size_t)NPTS * PQC);  // 128 KB
  unsigned short* W2Tlo = W2Thi + (size_t)OUTC2 * OUTC2;               // 128 KB
  // x4 aliases h's first 128KB: knn3 finishes before edgeconv1 writes h.
  float4* x4 = (float4*)h;

  pack_x_kernel<<<(NPTS + 255) / 256, 256, 0, stream>>>(x, x4);
  prep_w1_kernel<<<(HIDC * PQC) / 256, 256, 0, stream>>>(W2a, Wc);
  prep_w2_kernel<<<OUTC2, OUTC2, 0, stream>>>(W2b, W2Thi, W2Tlo);
  knn3_kernel<<<NPTS / 4, 256, 0, stream>>>(x4, idx1);
  edgeconv1_kernel<<<NPTS / 8, 256, 0, stream>>>(x, idx1, W1a, b1a, W1b, b1b,
                                                 h, Hhi, Hlo, sq2);
  gemm_pq_kernel<<<(NPTS / 32) * 8, 256, 0, stream>>>(h, Wc, b2a, PQ);
  knn128_filter_kernel<<<(NPTS / 64) * JSPLIT, 256, 0, stream>>>(Hhi, Hlo, sq2, pi2);
  knn_rescore_kernel<<<NPTS / 4, 256, 0, stream>>>(h, sq2, pi2, idx2);
  edgeconv2_kernel<<<NPTS / 4, 256, 0, stream>>>(PQ, idx2, W2Thi, W2Tlo, b2b, out);
}

// Round 14
// 359.873 us; speedup vs baseline: 1.2212x; 1.2212x over previous
//
#include <hip/hip_runtime.h>
#include <math.h>

constexpr int NPTS  = 8192;
constexpr int HIDC  = 128;
constexpr int OUTC2 = 256;
constexpr int PQC   = 512;
constexpr int KK1   = 16;
constexpr int KK2   = 8;

typedef __attribute__((ext_vector_type(8))) short short8;
typedef __attribute__((ext_vector_type(4))) float f32x4;

__device__ __forceinline__ f32x4 mfma16(short8 a, short8 b, f32x4 c) {
  return __builtin_amdgcn_mfma_f32_16x16x32_bf16(a, b, c, 0, 0, 0);
}

__device__ __forceinline__ void async_ld16(void* lds, const void* g) {
  __builtin_amdgcn_global_load_lds(
      (const __attribute__((address_space(1))) unsigned int*)g,
      (__attribute__((address_space(3))) unsigned int*)lds, 16, 0, 0);
}

// packed-key insert: keys unique (j embedded) -> strict < is exact lex.
template <int K>
__device__ __forceinline__ void ins_u(unsigned (&kk)[K], unsigned v) {
  if (v < kk[K - 1]) {
    kk[K - 1] = v;
    #pragma unroll
    for (int p = K - 1; p > 0; --p) {
      unsigned a = kk[p - 1], b = kk[p];
      kk[p - 1] = a < b ? a : b;
      kk[p]     = a < b ? b : a;
    }
  }
}

// lexicographic (d, idx) insert — exact fp32 merging.
template <int K>
__device__ __forceinline__ void ins_lex(float (&kf)[K], int (&ki)[K], float v, int j) {
  bool ins = (v < kf[K - 1]) || (v == kf[K - 1] && j < ki[K - 1]);
  if (ins) {
    kf[K - 1] = v; ki[K - 1] = j;
    #pragma unroll
    for (int p = K - 1; p > 0; --p) {
      float fa = kf[p - 1], fb = kf[p];
      int   ia = ki[p - 1], ib = ki[p];
      bool sw = (fb < fa) || (fb == fa && ib < ia);
      kf[p - 1] = sw ? fb : fa; ki[p - 1] = sw ? ib : ia;
      kf[p]     = sw ? fa : fb; ki[p]     = sw ? ia : ib;
    }
  }
}

__device__ __forceinline__ unsigned short bf16_rn(float x) {
  unsigned int u = __float_as_uint(x);
  unsigned int r = u + 0x7fffu + ((u >> 16) & 1u);
  return (unsigned short)(r >> 16);
}

// ---------------------------------------------------------------- pack x
__global__ void pack_x_kernel(const float* __restrict__ x, float4* __restrict__ x4) {
  int i = blockIdx.x * blockDim.x + threadIdx.x;
  if (i < NPTS) {
    float a = x[3 * i], b = x[3 * i + 1], c = x[3 * i + 2];
    x4[i] = make_float4(a, b, c, a * a + b * b + c * c);
  }
}

// ---------------------------------------------------------------- Wc = [Wl-Wh | Wh] for layer2 stage1
__global__ void prep_w1_kernel(const float* __restrict__ W1, float* __restrict__ Wc) {
  int idx = blockIdx.x * 256 + threadIdx.x;    // 128*512
  int k = idx >> 9, c = idx & 511;
  float wh = W1[(size_t)(HIDC + k) * OUTC2 + (c & 255)];
  Wc[idx] = (c < OUTC2) ? (W1[(size_t)k * OUTC2 + c] - wh) : wh;
}

// ---------------------------------------------------------------- W2 -> MFMA-fragment-major bf16 hi/lo
// W2F[((s*16 + nt)*64 + lane)*8 + e] = W2[k][c], where c = nt*16 + ct,
// k = s*32 + kg*8 + e, lane = kg*16 + ct. Each k-slice s is a contiguous
// 16 KB block -> coalesced global_load_lds staging, contiguous frag reads.
__global__ void prep_w2_kernel(const float* __restrict__ W2,
                               unsigned short* __restrict__ W2Fhi,
                               unsigned short* __restrict__ W2Flo) {
  const int c = blockIdx.x;      // out channel 0..255
  const int k = threadIdx.x;     // inner dim   0..255
  float w = W2[(size_t)k * OUTC2 + c];
  unsigned short hi = bf16_rn(w);
  float fh = __uint_as_float(((unsigned int)hi) << 16);
  unsigned short lo = bf16_rn(w - fh);
  const int nt = c >> 4, ct = c & 15;
  const int s  = k >> 5, kg = (k >> 3) & 3, e = k & 7;
  const int lane = kg * 16 + ct;
  const size_t idx = ((size_t)(s * 16 + nt) * 64 + lane) * 8 + e;
  W2Fhi[idx] = hi;
  W2Flo[idx] = lo;
}

// ---------------------------------------------------------------- KNN1 (C=3, K=16) — unchanged (R11-validated)
__global__ __launch_bounds__(256) void knn3_kernel(const float4* __restrict__ X4,
                                                   int* __restrict__ idx_out) {
  const int tid  = threadIdx.x;
  const int lane = tid & 63;
  const int wv   = __builtin_amdgcn_readfirstlane(tid >> 6);
  const int q    = blockIdx.x * 4 + wv;

  const float4 qv = X4[q];

  unsigned kk[KK2];
  #pragma unroll
  for (int k = 0; k < KK2; ++k) kk[k] = 0xFFFFFFFFu;

  for (int c = 0; c < NPTS / 64; ++c) {
    const int j = c * 64 + lane;
    float4 pj = X4[j];
    float d = fmaxf(qv.w + pj.w - 2.f * (qv.x * pj.x + qv.y * pj.y + qv.z * pj.z), 0.f);
    unsigned key = (__float_as_uint(d) & 0xFFFFE000u) | (unsigned)j;
    if (j == q) key = 0xFFFFFFFFu;
    ins_u<KK2>(kk, key);
  }

  float kf[KK2]; int kj[KK2];
  #pragma unroll
  for (int k = 0; k < KK2; ++k) { kf[k] = INFINITY; kj[k] = 0x7fffffff; }
  #pragma unroll
  for (int k = 0; k < KK2; ++k) {
    int j = (int)(kk[k] & 0x1FFFu);
    float4 pj = X4[j];
    float d = qv.w + pj.w - 2.f * (qv.x * pj.x + qv.y * pj.y + qv.z * pj.z);
    if (kk[k] == 0xFFFFFFFFu) { d = INFINITY; j = 0x7fffffff; }
    ins_lex<KK2>(kf, kj, d, j);
  }

  #pragma unroll
  for (int k = 0; k < KK1; ++k) {
    float mf = kf[0]; int mj = kj[0];
    #pragma unroll
    for (int m = 1; m <= 32; m <<= 1) {
      float of = __shfl_xor(mf, m, 64);
      int   oj = __shfl_xor(mj, m, 64);
      bool g = (of < mf) || (of == mf && oj < mj);
      mf = g ? of : mf; mj = g ? oj : mj;
    }
    const bool won = (kf[0] == mf) && (kj[0] == mj);
    if (won) {
      idx_out[(size_t)q * KK1 + k] = mj;
      #pragma unroll
      for (int p = 0; p < KK2 - 1; ++p) { kf[p] = kf[p + 1]; kj[p] = kj[p + 1]; }
      kf[KK2 - 1] = INFINITY; kj[KK2 - 1] = 0x7fffffff;
    }
  }
}

// ---------------------------------------------------------------- EdgeConv 1 (unchanged)
__global__ __launch_bounds__(256) void edgeconv1_kernel(
    const float* __restrict__ X, const int* __restrict__ knn,
    const float* __restrict__ W1, const float* __restrict__ b1,
    const float* __restrict__ W2, const float* __restrict__ b2,
    float* __restrict__ H, unsigned short* __restrict__ Hhi,
    unsigned short* __restrict__ Hlo, float* __restrict__ SQ2) {
  __shared__ float h1[8][KK1][HIDC];
  __shared__ float xjs[8][KK1][3];
  __shared__ float xis[8][3];
  const int tid  = threadIdx.x;
  const int lane = tid & 63;
  const int wv   = __builtin_amdgcn_readfirstlane(tid >> 6);
  const int half = lane >> 5;
  const int hl   = lane & 31;
  const int lp   = wv * 2 + half;
  const int p    = blockIdx.x * 8 + lp;
  const int ch0  = hl * 4;

  if (hl < KK1) {
    int j = knn[p * KK1 + hl];
    xjs[lp][hl][0] = X[3 * j]; xjs[lp][hl][1] = X[3 * j + 1]; xjs[lp][hl][2] = X[3 * j + 2];
  } else if (hl < KK1 + 3) {
    xis[lp][hl - KK1] = X[3 * p + hl - KK1];
  }
  __syncthreads();

  f32x4 w1r[6];
  #pragma unroll
  for (int c = 0; c < 6; ++c) w1r[c] = *(const f32x4*)&W1[c * HIDC + ch0];
  f32x4 b1v = *(const f32x4*)&b1[ch0];
  const float xi0 = xis[lp][0], xi1 = xis[lp][1], xi2 = xis[lp][2];
  f32x4 base;
  #pragma unroll
  for (int c = 0; c < 4; ++c)
    base[c] = b1v[c] + xi0 * w1r[0][c] + xi1 * w1r[1][c] + xi2 * w1r[2][c];
  #pragma unroll
  for (int e = 0; e < KK1; ++e) {
    float dx = xjs[lp][e][0] - xi0, dy = xjs[lp][e][1] - xi1, dz = xjs[lp][e][2] - xi2;
    f32x4 v;
    #pragma unroll
    for (int c = 0; c < 4; ++c)
      v[c] = fmaxf(base[c] + dx * w1r[3][c] + dy * w1r[4][c] + dz * w1r[5][c], 0.f);
    *(f32x4*)&h1[lp][e][ch0] = v;
  }
  __syncthreads();

  float acc[KK1][4];
  #pragma unroll
  for (int e = 0; e < KK1; ++e)
    #pragma unroll
    for (int c = 0; c < 4; ++c) acc[e][c] = 0.f;
  for (int c4 = 0; c4 < HIDC / 4; ++c4) {
    f32x4 w2r[4];
    #pragma unroll
    for (int cc = 0; cc < 4; ++cc)
      w2r[cc] = *(const f32x4*)&W2[(c4 * 4 + cc) * HIDC + ch0];
    #pragma unroll
    for (int e = 0; e < KK1; ++e) {
      f32x4 hv = *(const f32x4*)&h1[lp][e][c4 * 4];
      #pragma unroll
      for (int cc = 0; cc < 4; ++cc)
        #pragma unroll
        for (int c = 0; c < 4; ++c) acc[e][c] += hv[cc] * w2r[cc][c];
    }
  }
  f32x4 b2v = *(const f32x4*)&b2[ch0];
  f32x4 outv;
  #pragma unroll
  for (int c = 0; c < 4; ++c) {
    float m = -INFINITY;
    #pragma unroll
    for (int e = 0; e < KK1; ++e) m = fmaxf(m, acc[e][c]);
    outv[c] = m + b2v[c];
  }
  *(f32x4*)&H[(size_t)p * HIDC + ch0] = outv;

  unsigned short hb[4], lb[4];
  #pragma unroll
  for (int c = 0; c < 4; ++c) {
    hb[c] = bf16_rn(outv[c]);
    float fh = __uint_as_float(((unsigned int)hb[c]) << 16);
    lb[c] = bf16_rn(outv[c] - fh);
  }
  *(ushort4*)&Hhi[(size_t)p * HIDC + ch0] = make_ushort4(hb[0], hb[1], hb[2], hb[3]);
  *(ushort4*)&Hlo[(size_t)p * HIDC + ch0] = make_ushort4(lb[0], lb[1], lb[2], lb[3]);

  float s = outv[0]*outv[0] + outv[1]*outv[1] + outv[2]*outv[2] + outv[3]*outv[3];
  #pragma unroll
  for (int m = 1; m <= 16; m <<= 1) s += __shfl_xor(s, m, 64);
  if (hl == 0) SQ2[p] = s;
}

// ---------------------------------------------------------------- PQ = H @ Wc (+b1 on P half)
__global__ __launch_bounds__(256) void gemm_pq_kernel(
    const float* __restrict__ H, const float* __restrict__ Wc,
    const float* __restrict__ b1, float* __restrict__ PQ) {
  __shared__ float Hs[32][HIDC];
  const int tid = threadIdx.x;
  const int rb  = blockIdx.x >> 3;
  const int cb  = blockIdx.x & 7;
  const int col = cb * 64 + (tid & 63);
  const int rg  = tid >> 6;

  #pragma unroll
  for (int u = 0; u < 4; ++u) {
    int idx = u * 256 + tid;
    int r = idx >> 5, k4 = idx & 31;
    *(f32x4*)&Hs[r][k4 * 4] = *(const f32x4*)&H[(size_t)(rb * 32 + r) * HIDC + k4 * 4];
  }
  __syncthreads();

  float acc[8] = {};
  for (int k = 0; k < HIDC; ++k) {
    float w = Wc[(size_t)k * PQC + col];
    #pragma unroll
    for (int i = 0; i < 8; ++i) acc[i] += Hs[rg * 8 + i][k] * w;
  }
  const float bb = (col < OUTC2) ? b1[col] : 0.f;
  #pragma unroll
  for (int i = 0; i < 8; ++i)
    PQ[(size_t)(rb * 32 + rg * 8 + i) * PQC + col] = acc[i] + bb;
}

// ---------------------------------------------------------------- KNN2 filter (unchanged from R10)
constexpr int JSPLIT = 16;
constexpr int JPB2   = NPTS / JSPLIT;
constexpr int NCH    = JPB2 / 16;
constexpr int CPQ    = JSPLIT * KK2;

__global__ __launch_bounds__(256) void knn128_filter_kernel(
    const unsigned short* __restrict__ Hhi, const unsigned short* __restrict__ Hlo,
    const float* __restrict__ SQ, int* __restrict__ pi2) {
  __shared__ __align__(16) unsigned short As[2][2][16 * HIDC];
  const int tid  = threadIdx.x;
  const int lane = tid & 63;
  const int wv   = __builtin_amdgcn_readfirstlane(tid >> 6);
  const int qb   = blockIdx.x >> 4;
  const int js   = blockIdx.x & 15;
  const int col  = lane & 15;
  const int kg   = lane >> 4;
  const int qg   = qb * 64 + wv * 16 + col;

  short8 qhi[4], qlo[4];
  #pragma unroll
  for (int s = 0; s < 4; ++s) {
    const size_t o = (size_t)qg * HIDC + s * 32 + kg * 8;
    qhi[s] = *reinterpret_cast<const short8*>(Hhi + o);
    qlo[s] = *reinterpret_cast<const short8*>(Hlo + o);
  }
  const float sqq = SQ[qg];

  unsigned kk[KK2];
  #pragma unroll
  for (int k = 0; k < KK2; ++k) kk[k] = 0xFFFFFFFFu;

  const int jbase = js * JPB2;

  const int srow = 4 * wv + (lane >> 4);
  const int sslt = (lane & 15) ^ (srow & 7);
  auto stage = [&](int buf, int ch) {
    const size_t gofs = (size_t)(jbase + ch * 16 + srow) * HIDC + sslt * 8;
    async_ld16((char*)&As[buf][0][0] + wv * 1024, Hhi + gofs);
    async_ld16((char*)&As[buf][1][0] + wv * 1024, Hlo + gofs);
  };

  stage(0, 0);
  asm volatile("s_waitcnt vmcnt(0)" ::: "memory");
  __syncthreads();

  for (int ch = 0; ch < NCH; ++ch) {
    const int cur = ch & 1;
    if (ch + 1 < NCH) stage(cur ^ 1, ch + 1);

    const int jb = jbase + ch * 16;
    short8 ahi[4], alo[4];
    const int rowb = col * 256;
    #pragma unroll
    for (int s = 0; s < 4; ++s) {
      const int sl = ((s * 4 + kg) ^ (col & 7)) * 16;
      ahi[s] = *(const short8*)((const char*)&As[cur][0][0] + rowb + sl);
      alo[s] = *(const short8*)((const char*)&As[cur][1][0] + rowb + sl);
    }
    f32x4 sqjv = *reinterpret_cast<const f32x4*>(SQ + jb + kg * 4);

    f32x4 acc = {0.f, 0.f, 0.f, 0.f};
    #pragma unroll
    for (int s = 0; s < 4; ++s) {
      acc = mfma16(ahi[s], qhi[s], acc);
      acc = mfma16(ahi[s], qlo[s], acc);
      acc = mfma16(alo[s], qhi[s], acc);
    }
    #pragma unroll
    for (int r = 0; r < 4; ++r) {
      const int jg = jb + kg * 4 + r;
      float d = fmaxf(sqq + sqjv[r] - 2.f * acc[r], 0.f);
      unsigned key = (__float_as_uint(d) & 0xFFFFE000u) | (unsigned)jg;
      if (jg == qg) key = 0xFFFFFFFFu;
      ins_u<KK2>(kk, key);
    }
    asm volatile("s_waitcnt vmcnt(0)" ::: "memory");
    __syncthreads();
  }

  #pragma unroll
  for (int dlt = 16; dlt <= 32; dlt <<= 1) {
    unsigned ok[KK2];
    #pragma unroll
    for (int k = 0; k < KK2; ++k) ok[k] = __shfl_xor((int)kk[k], dlt, 64);
    #pragma unroll
    for (int k = 0; k < KK2; ++k) ins_u<KK2>(kk, ok[k]);
  }
  if (lane < 16) {
    const size_t base = (size_t)qg * CPQ + js * KK2;
    #pragma unroll
    for (int k = 0; k < KK2; ++k) pi2[base + k] = (int)(kk[k] & 0x1FFFu);
  }
}

// ---------------------------------------------------------------- exact fp32 rescore (unchanged)
__global__ __launch_bounds__(256) void knn_rescore_kernel(
    const float* __restrict__ H, const float* __restrict__ SQ,
    const int* __restrict__ pi2, int* __restrict__ idx_out) {
  __shared__ float qrow[4][HIDC];
  const int tid  = threadIdx.x;
  const int wv   = tid >> 6;
  const int lane = tid & 63;
  const int q0   = blockIdx.x * 4;
  const int q    = q0 + wv;
  for (int u = tid; u < 4 * HIDC; u += 256)
    qrow[u >> 7][u & 127] = H[(size_t)(q0 + (u >> 7)) * HIDC + (u & 127)];
  __syncthreads();

  const int c0 = pi2[(size_t)q * CPQ + lane];
  const int c1 = pi2[(size_t)q * CPQ + 64 + lane];
  const float sqq = SQ[q];

  float dot0 = 0.f;
  {
    const float* crow = H + (size_t)c0 * HIDC;
    #pragma unroll 8
    for (int c4 = 0; c4 < HIDC / 4; ++c4) {
      f32x4 qv = *(const f32x4*)&qrow[wv][c4 * 4];
      f32x4 cv = *(const f32x4*)(crow + c4 * 4);
      dot0 += qv[0] * cv[0] + qv[1] * cv[1] + qv[2] * cv[2] + qv[3] * cv[3];
    }
  }
  float d0 = sqq + SQ[c0] - 2.f * dot0;

  float dot1 = 0.f;
  {
    const float* crow = H + (size_t)c1 * HIDC;
    #pragma unroll 8
    for (int c4 = 0; c4 < HIDC / 4; ++c4) {
      f32x4 qv = *(const f32x4*)&qrow[wv][c4 * 4];
      f32x4 cv = *(const f32x4*)(crow + c4 * 4);
      dot1 += qv[0] * cv[0] + qv[1] * cv[1] + qv[2] * cv[2] + qv[3] * cv[3];
    }
  }
  float d1 = sqq + SQ[c1] - 2.f * dot1;

  float kf[KK2]; int ki[KK2];
  kf[0] = d0; ki[0] = c0;
  #pragma unroll
  for (int k = 1; k < KK2; ++k) { kf[k] = INFINITY; ki[k] = 0x7fffffff; }
  ins_lex<KK2>(kf, ki, d1, c1);
  #pragma unroll
  for (int dlt = 1; dlt <= 32; dlt <<= 1) {
    float of[KK2]; int oi[KK2];
    #pragma unroll
    for (int k = 0; k < KK2; ++k) { of[k] = __shfl_xor(kf[k], dlt, 64); oi[k] = __shfl_xor(ki[k], dlt, 64); }
    #pragma unroll
    for (int k = 0; k < KK2; ++k) ins_lex<KK2>(kf, ki, of[k], oi[k]);
  }
  if (lane == 0) {
    #pragma unroll
    for (int k = 0; k < KK2; ++k) idx_out[(size_t)q * KK2 + k] = ki[k];
  }
}

// ---------------------------------------------------------------- EdgeConv 2 — MFMA, LDS-staged B
// Block = 8 points = 64 G rows, 512 thr (8 waves). Stage 1: wave wv builds
// g1 (bf16 hi/lo, XOR-swizzled LDS) for point p_base+wv (R12-validated).
// Stage 2: D(64x256) = G @ W2. B k-slices (16KB hi + 16KB lo) staged per
// block via coalesced global_load_lds from fragment-major W2F. FIX vs R13:
// per-lane global source (+lane*8 ushorts = 16B/lane) — gload_lds LDS dest
// is wave-uniform+lane*16 but the SOURCE must be per-lane (m104/m108).
__global__ __launch_bounds__(512) void edgeconv2_kernel(
    const float* __restrict__ PQ, const int* __restrict__ knn,
    const unsigned short* __restrict__ W2Fhi, const unsigned short* __restrict__ W2Flo,
    const float* __restrict__ b2, float* __restrict__ Out) {
  __shared__ __align__(16) unsigned short Ghi[64 * OUTC2];   // 32 KB
  __shared__ __align__(16) unsigned short Glo[64 * OUTC2];   // 32 KB
  __shared__ __align__(16) unsigned short Bs[2][2][8192];    // 64 KB (buf, hi/lo, 16KB slice)
  const int tid  = threadIdx.x;
  const int lane = tid & 63;
  const int wv   = __builtin_amdgcn_readfirstlane(tid >> 6);  // 0..7
  const int p_base = blockIdx.x * 8;

  // ---- stage 1: g1 for point p_base+wv (wave-per-point, R12 pattern)
  {
    const int p   = p_base + wv;
    const int ch0 = lane * 4;
    f32x4 pv = *(const f32x4*)&PQ[(size_t)p * PQC + ch0];
    #pragma unroll
    for (int e = 0; e < KK2; ++e) {
      const int j = knn[p * KK2 + e];
      f32x4 qv = *(const f32x4*)&PQ[(size_t)j * PQC + OUTC2 + ch0];
      unsigned short hb[4], lb[4];
      #pragma unroll
      for (int c = 0; c < 4; ++c) {
        float g = fmaxf(pv[c] + qv[c], 0.f);
        hb[c] = bf16_rn(g);
        float fh = __uint_as_float(((unsigned int)hb[c]) << 16);
        lb[c] = bf16_rn(g - fh);
      }
      const int r   = wv * 8 + e;                              // G row 0..63
      const int off = r * 512 + (((ch0 >> 3) ^ (r & 7)) << 4) + ((ch0 & 7) << 1);
      *(ushort4*)((char*)Ghi + off) = make_ushort4(hb[0], hb[1], hb[2], hb[3]);
      *(ushort4*)((char*)Glo + off) = make_ushort4(lb[0], lb[1], lb[2], lb[3]);
    }
  }

  // ---- B slice staging: per-lane source (lane*8 ushorts), linear LDS copy
  auto stageB = [&](int buf, int s) {
    #pragma unroll
    for (int i = 0; i < 2; ++i) {
      const size_t go = (size_t)s * 8192 + (size_t)(wv * 2 + i) * 512 + (size_t)lane * 8;
      async_ld16((char*)&Bs[buf][0][0] + (wv * 2 + i) * 1024, W2Fhi + go);
      async_ld16((char*)&Bs[buf][1][0] + (wv * 2 + i) * 1024, W2Flo + go);
    }
  };

  stageB(0, 0);
  asm volatile("s_waitcnt vmcnt(0)" ::: "memory");
  __syncthreads();   // G ready + B slice 0 ready

  // ---- stage 2: wave = M-tile mt = wv&3, N-half nh = wv>>2
  const int col = lane & 15;
  const int kg  = lane >> 4;
  const int mt  = wv & 3;
  const int nh  = wv >> 2;
  const int ar  = mt * 16 + col;            // G row this lane's A-frag covers
  const int abase = ar * 512;

  f32x4 acc[8];
  #pragma unroll
  for (int n = 0; n < 8; ++n) acc[n] = (f32x4){0.f, 0.f, 0.f, 0.f};

  for (int s = 0; s < 8; ++s) {             // K-steps of 32
    const int cur = s & 1;
    if (s + 1 < 8) stageB(cur ^ 1, s + 1);

    const int asl = (((s * 4 + kg) ^ (ar & 7)) << 4);
    short8 ghi = *(const short8*)((const char*)Ghi + abase + asl);
    short8 glo = *(const short8*)((const char*)Glo + abase + asl);
    #pragma unroll
    for (int n = 0; n < 8; ++n) {
      const int nt = nh * 8 + n;
      const int bo = (nt * 64 + lane) * 16;   // bytes into the slice
      short8 bhi = *(const short8*)((const char*)&Bs[cur][0][0] + bo);
      short8 blo = *(const short8*)((const char*)&Bs[cur][1][0] + bo);
      acc[n] = mfma16(ghi, bhi, acc[n]);
      acc[n] = mfma16(ghi, blo, acc[n]);
      acc[n] = mfma16(glo, bhi, acc[n]);
    }
    asm volatile("s_waitcnt vmcnt(0)" ::: "memory");
    __syncthreads();
  }

  // ---- epilogue (R12-validated mapping): D row = kg*4+reg (edge),
  // kg 0/1 -> point 2mt, kg 2/3 -> point 2mt+1; col = nt*16+col (channel)
  const int pt = p_base + mt * 2 + (kg >> 1);
  #pragma unroll
  for (int n = 0; n < 8; ++n) {
    float m = fmaxf(fmaxf(acc[n][0], acc[n][1]), fmaxf(acc[n][2], acc[n][3]));
    m = fmaxf(m, __shfl_xor(m, 16, 64));
    if ((kg & 1) == 0) {
      const int ncol = nh * 128 + n * 16 + col;
      Out[(size_t)pt * OUTC2 + ncol] = m + b2[ncol];
    }
  }
}

// ---------------------------------------------------------------- launch
extern "C" void kernel_launch(void* const* d_in, const int* in_sizes, int n_in,
                              void* d_out, int out_size, void* d_ws, size_t ws_size,
                              hipStream_t stream) {
  const float* x   = (const float*)d_in[0];
  const float* W1a = (const float*)d_in[1];
  const float* b1a = (const float*)d_in[2];
  const float* W1b = (const float*)d_in[3];
  const float* b1b = (const float*)d_in[4];
  const float* W2a = (const float*)d_in[5];
  const float* b2a = (const float*)d_in[6];
  const float* W2b = (const float*)d_in[7];
  const float* b2b = (const float*)d_in[8];
  float* out = (float*)d_out;

  float* h    = (float*)d_ws;                       // 4 MB
  float* sq2  = h + (size_t)NPTS * HIDC;
  int*   idx1 = (int*)(sq2 + NPTS);
  int*   idx2 = idx1 + (size_t)NPTS * KK1;
  unsigned short* Hhi = (unsigned short*)(idx2 + (size_t)NPTS * KK2);  // 2 MB
  unsigned short* Hlo = Hhi + (size_t)NPTS * HIDC;                     // 2 MB
  int*   pi2  = (int*)(Hlo + (size_t)NPTS * HIDC);  // 4 MB
  float* Wc   = (float*)(pi2 + (size_t)NPTS * CPQ); // 256 KB
  float* PQ   = Wc + (size_t)HIDC * PQC;            // 16 MB
  unsigned short* W2Fhi = (unsigned short*)(PQ + (size_t)NPTS * PQC);  // 128 KB
  unsigned short* W2Flo = W2Fhi + (size_t)OUTC2 * OUTC2;               // 128 KB
  // x4 aliases h's first 128KB: knn3 finishes before edgeconv1 writes h.
  float4* x4 = (float4*)h;

  pack_x_kernel<<<(NPTS + 255) / 256, 256, 0, stream>>>(x, x4);
  prep_w1_kernel<<<(HIDC * PQC) / 256, 256, 0, stream>>>(W2a, Wc);
  prep_w2_kernel<<<OUTC2, OUTC2, 0, stream>>>(W2b, W2Fhi, W2Flo);
  knn3_kernel<<<NPTS / 4, 256, 0, stream>>>(x4, idx1);
  edgeconv1_kernel<<<NPTS / 8, 256, 0, stream>>>(x, idx1, W1a, b1a, W1b, b1b,
                                                 h, Hhi, Hlo, sq2);
  gemm_pq_kernel<<<(NPTS / 32) * 8, 256, 0, stream>>>(h, Wc, b2a, PQ);
  knn128_filter_kernel<<<(NPTS / 64) * JSPLIT, 256, 0, stream>>>(Hhi, Hlo, sq2, pi2);
  knn_rescore_kernel<<<NPTS / 4, 256, 0, stream>>>(h, sq2, pi2, idx2);
  edgeconv2_kernel<<<NPTS / 8, 512, 0, stream>>>(PQ, idx2, W2Fhi, W2Flo, b2b, out);
}

// Round 15
// 303.637 us; speedup vs baseline: 1.4473x; 1.1852x over previous
//
#include <hip/hip_runtime.h>
#include <math.h>

constexpr int NPTS  = 8192;
constexpr int HIDC  = 128;
constexpr int OUTC2 = 256;
constexpr int PQC   = 512;
constexpr int KK1   = 16;
constexpr int KK2   = 8;

typedef __attribute__((ext_vector_type(8))) short short8;
typedef __attribute__((ext_vector_type(4))) float f32x4;

__device__ __forceinline__ f32x4 mfma16(short8 a, short8 b, f32x4 c) {
  return __builtin_amdgcn_mfma_f32_16x16x32_bf16(a, b, c, 0, 0, 0);
}

__device__ __forceinline__ void async_ld16(void* lds, const void* g) {
  __builtin_amdgcn_global_load_lds(
      (const __attribute__((address_space(1))) unsigned int*)g,
      (__attribute__((address_space(3))) unsigned int*)lds, 16, 0, 0);
}

// packed-key insert: keys unique (j embedded) -> strict < is exact lex.
template <int K>
__device__ __forceinline__ void ins_u(unsigned (&kk)[K], unsigned v) {
  if (v < kk[K - 1]) {
    kk[K - 1] = v;
    #pragma unroll
    for (int p = K - 1; p > 0; --p) {
      unsigned a = kk[p - 1], b = kk[p];
      kk[p - 1] = a < b ? a : b;
      kk[p]     = a < b ? b : a;
    }
  }
}

// lexicographic (d, idx) insert — exact fp32 merging.
template <int K>
__device__ __forceinline__ void ins_lex(float (&kf)[K], int (&ki)[K], float v, int j) {
  bool ins = (v < kf[K - 1]) || (v == kf[K - 1] && j < ki[K - 1]);
  if (ins) {
    kf[K - 1] = v; ki[K - 1] = j;
    #pragma unroll
    for (int p = K - 1; p > 0; --p) {
      float fa = kf[p - 1], fb = kf[p];
      int   ia = ki[p - 1], ib = ki[p];
      bool sw = (fb < fa) || (fb == fa && ib < ia);
      kf[p - 1] = sw ? fb : fa; ki[p - 1] = sw ? ib : ia;
      kf[p]     = sw ? fa : fb; ki[p]     = sw ? ia : ib;
    }
  }
}

__device__ __forceinline__ unsigned short bf16_rn(float x) {
  unsigned int u = __float_as_uint(x);
  unsigned int r = u + 0x7fffu + ((u >> 16) & 1u);
  return (unsigned short)(r >> 16);
}

// ---------------------------------------------------------------- pack x
__global__ void pack_x_kernel(const float* __restrict__ x, float4* __restrict__ x4) {
  int i = blockIdx.x * blockDim.x + threadIdx.x;
  if (i < NPTS) {
    float a = x[3 * i], b = x[3 * i + 1], c = x[3 * i + 2];
    x4[i] = make_float4(a, b, c, a * a + b * b + c * c);
  }
}

// ---------------------------------------------------------------- Wc = [Wl-Wh | Wh] for layer2 stage1
__global__ void prep_w1_kernel(const float* __restrict__ W1, float* __restrict__ Wc) {
  int idx = blockIdx.x * 256 + threadIdx.x;    // 128*512
  int k = idx >> 9, c = idx & 511;
  float wh = W1[(size_t)(HIDC + k) * OUTC2 + (c & 255)];
  Wc[idx] = (c < OUTC2) ? (W1[(size_t)k * OUTC2 + c] - wh) : wh;
}

// ---------------------------------------------------------------- W2 -> MFMA-fragment-major bf16 hi/lo
__global__ void prep_w2_kernel(const float* __restrict__ W2,
                               unsigned short* __restrict__ W2Fhi,
                               unsigned short* __restrict__ W2Flo) {
  const int c = blockIdx.x;      // out channel 0..255
  const int k = threadIdx.x;     // inner dim   0..255
  float w = W2[(size_t)k * OUTC2 + c];
  unsigned short hi = bf16_rn(w);
  float fh = __uint_as_float(((unsigned int)hi) << 16);
  unsigned short lo = bf16_rn(w - fh);
  const int nt = c >> 4, ct = c & 15;
  const int s  = k >> 5, kg = (k >> 3) & 3, e = k & 7;
  const int lane = kg * 16 + ct;
  const size_t idx = ((size_t)(s * 16 + nt) * 64 + lane) * 8 + e;
  W2Fhi[idx] = hi;
  W2Flo[idx] = lo;
}

// ---------------------------------------------------------------- KNN1 (C=3, K=16) — unchanged (R11-validated)
__global__ __launch_bounds__(256) void knn3_kernel(const float4* __restrict__ X4,
                                                   int* __restrict__ idx_out) {
  const int tid  = threadIdx.x;
  const int lane = tid & 63;
  const int wv   = __builtin_amdgcn_readfirstlane(tid >> 6);
  const int q    = blockIdx.x * 4 + wv;

  const float4 qv = X4[q];

  unsigned kk[KK2];
  #pragma unroll
  for (int k = 0; k < KK2; ++k) kk[k] = 0xFFFFFFFFu;

  for (int c = 0; c < NPTS / 64; ++c) {
    const int j = c * 64 + lane;
    float4 pj = X4[j];
    float d = fmaxf(qv.w + pj.w - 2.f * (qv.x * pj.x + qv.y * pj.y + qv.z * pj.z), 0.f);
    unsigned key = (__float_as_uint(d) & 0xFFFFE000u) | (unsigned)j;
    if (j == q) key = 0xFFFFFFFFu;
    ins_u<KK2>(kk, key);
  }

  float kf[KK2]; int kj[KK2];
  #pragma unroll
  for (int k = 0; k < KK2; ++k) { kf[k] = INFINITY; kj[k] = 0x7fffffff; }
  #pragma unroll
  for (int k = 0; k < KK2; ++k) {
    int j = (int)(kk[k] & 0x1FFFu);
    float4 pj = X4[j];
    float d = qv.w + pj.w - 2.f * (qv.x * pj.x + qv.y * pj.y + qv.z * pj.z);
    if (kk[k] == 0xFFFFFFFFu) { d = INFINITY; j = 0x7fffffff; }
    ins_lex<KK2>(kf, kj, d, j);
  }

  #pragma unroll
  for (int k = 0; k < KK1; ++k) {
    float mf = kf[0]; int mj = kj[0];
    #pragma unroll
    for (int m = 1; m <= 32; m <<= 1) {
      float of = __shfl_xor(mf, m, 64);
      int   oj = __shfl_xor(mj, m, 64);
      bool g = (of < mf) || (of == mf && oj < mj);
      mf = g ? of : mf; mj = g ? oj : mj;
    }
    const bool won = (kf[0] == mf) && (kj[0] == mj);
    if (won) {
      idx_out[(size_t)q * KK1 + k] = mj;
      #pragma unroll
      for (int p = 0; p < KK2 - 1; ++p) { kf[p] = kf[p + 1]; kj[p] = kj[p + 1]; }
      kf[KK2 - 1] = INFINITY; kj[KK2 - 1] = 0x7fffffff;
    }
  }
}

// ---------------------------------------------------------------- EdgeConv 1 (unchanged)
__global__ __launch_bounds__(256) void edgeconv1_kernel(
    const float* __restrict__ X, const int* __restrict__ knn,
    const float* __restrict__ W1, const float* __restrict__ b1,
    const float* __restrict__ W2, const float* __restrict__ b2,
    float* __restrict__ H, unsigned short* __restrict__ Hhi,
    unsigned short* __restrict__ Hlo, float* __restrict__ SQ2) {
  __shared__ float h1[8][KK1][HIDC];
  __shared__ float xjs[8][KK1][3];
  __shared__ float xis[8][3];
  const int tid  = threadIdx.x;
  const int lane = tid & 63;
  const int wv   = __builtin_amdgcn_readfirstlane(tid >> 6);
  const int half = lane >> 5;
  const int hl   = lane & 31;
  const int lp   = wv * 2 + half;
  const int p    = blockIdx.x * 8 + lp;
  const int ch0  = hl * 4;

  if (hl < KK1) {
    int j = knn[p * KK1 + hl];
    xjs[lp][hl][0] = X[3 * j]; xjs[lp][hl][1] = X[3 * j + 1]; xjs[lp][hl][2] = X[3 * j + 2];
  } else if (hl < KK1 + 3) {
    xis[lp][hl - KK1] = X[3 * p + hl - KK1];
  }
  __syncthreads();

  f32x4 w1r[6];
  #pragma unroll
  for (int c = 0; c < 6; ++c) w1r[c] = *(const f32x4*)&W1[c * HIDC + ch0];
  f32x4 b1v = *(const f32x4*)&b1[ch0];
  const float xi0 = xis[lp][0], xi1 = xis[lp][1], xi2 = xis[lp][2];
  f32x4 base;
  #pragma unroll
  for (int c = 0; c < 4; ++c)
    base[c] = b1v[c] + xi0 * w1r[0][c] + xi1 * w1r[1][c] + xi2 * w1r[2][c];
  #pragma unroll
  for (int e = 0; e < KK1; ++e) {
    float dx = xjs[lp][e][0] - xi0, dy = xjs[lp][e][1] - xi1, dz = xjs[lp][e][2] - xi2;
    f32x4 v;
    #pragma unroll
    for (int c = 0; c < 4; ++c)
      v[c] = fmaxf(base[c] + dx * w1r[3][c] + dy * w1r[4][c] + dz * w1r[5][c], 0.f);
    *(f32x4*)&h1[lp][e][ch0] = v;
  }
  __syncthreads();

  float acc[KK1][4];
  #pragma unroll
  for (int e = 0; e < KK1; ++e)
    #pragma unroll
    for (int c = 0; c < 4; ++c) acc[e][c] = 0.f;
  for (int c4 = 0; c4 < HIDC / 4; ++c4) {
    f32x4 w2r[4];
    #pragma unroll
    for (int cc = 0; cc < 4; ++cc)
      w2r[cc] = *(const f32x4*)&W2[(c4 * 4 + cc) * HIDC + ch0];
    #pragma unroll
    for (int e = 0; e < KK1; ++e) {
      f32x4 hv = *(const f32x4*)&h1[lp][e][c4 * 4];
      #pragma unroll
      for (int cc = 0; cc < 4; ++cc)
        #pragma unroll
        for (int c = 0; c < 4; ++c) acc[e][c] += hv[cc] * w2r[cc][c];
    }
  }
  f32x4 b2v = *(const f32x4*)&b2[ch0];
  f32x4 outv;
  #pragma unroll
  for (int c = 0; c < 4; ++c) {
    float m = -INFINITY;
    #pragma unroll
    for (int e = 0; e < KK1; ++e) m = fmaxf(m, acc[e][c]);
    outv[c] = m + b2v[c];
  }
  *(f32x4*)&H[(size_t)p * HIDC + ch0] = outv;

  unsigned short hb[4], lb[4];
  #pragma unroll
  for (int c = 0; c < 4; ++c) {
    hb[c] = bf16_rn(outv[c]);
    float fh = __uint_as_float(((unsigned int)hb[c]) << 16);
    lb[c] = bf16_rn(outv[c] - fh);
  }
  *(ushort4*)&Hhi[(size_t)p * HIDC + ch0] = make_ushort4(hb[0], hb[1], hb[2], hb[3]);
  *(ushort4*)&Hlo[(size_t)p * HIDC + ch0] = make_ushort4(lb[0], lb[1], lb[2], lb[3]);

  float s = outv[0]*outv[0] + outv[1]*outv[1] + outv[2]*outv[2] + outv[3]*outv[3];
  #pragma unroll
  for (int m = 1; m <= 16; m <<= 1) s += __shfl_xor(s, m, 64);
  if (hl == 0) SQ2[p] = s;
}

// ---------------------------------------------------------------- PQ = H @ Wc (+b1 on P half)
__global__ __launch_bounds__(256) void gemm_pq_kernel(
    const float* __restrict__ H, const float* __restrict__ Wc,
    const float* __restrict__ b1, float* __restrict__ PQ) {
  __shared__ float Hs[32][HIDC];
  const int tid = threadIdx.x;
  const int rb  = blockIdx.x >> 3;
  const int cb  = blockIdx.x & 7;
  const int col = cb * 64 + (tid & 63);
  const int rg  = tid >> 6;

  #pragma unroll
  for (int u = 0; u < 4; ++u) {
    int idx = u * 256 + tid;
    int r = idx >> 5, k4 = idx & 31;
    *(f32x4*)&Hs[r][k4 * 4] = *(const f32x4*)&H[(size_t)(rb * 32 + r) * HIDC + k4 * 4];
  }
  __syncthreads();

  float acc[8] = {};
  for (int k = 0; k < HIDC; ++k) {
    float w = Wc[(size_t)k * PQC + col];
    #pragma unroll
    for (int i = 0; i < 8; ++i) acc[i] += Hs[rg * 8 + i][k] * w;
  }
  const float bb = (col < OUTC2) ? b1[col] : 0.f;
  #pragma unroll
  for (int i = 0; i < 8; ++i)
    PQ[(size_t)(rb * 32 + rg * 8 + i) * PQC + col] = acc[i] + bb;
}

// ---------------------------------------------------------------- KNN2 filter (R10-validated; now stores KEYS)
constexpr int JSPLIT = 16;
constexpr int JPB2   = NPTS / JSPLIT;
constexpr int NCH    = JPB2 / 16;
constexpr int CPQ    = JSPLIT * KK2;   // 128 keys per query

__global__ __launch_bounds__(256) void knn128_filter_kernel(
    const unsigned short* __restrict__ Hhi, const unsigned short* __restrict__ Hlo,
    const float* __restrict__ SQ, unsigned* __restrict__ pk2) {
  __shared__ __align__(16) unsigned short As[2][2][16 * HIDC];
  const int tid  = threadIdx.x;
  const int lane = tid & 63;
  const int wv   = __builtin_amdgcn_readfirstlane(tid >> 6);
  const int qb   = blockIdx.x >> 4;
  const int js   = blockIdx.x & 15;
  const int col  = lane & 15;
  const int kg   = lane >> 4;
  const int qg   = qb * 64 + wv * 16 + col;

  short8 qhi[4], qlo[4];
  #pragma unroll
  for (int s = 0; s < 4; ++s) {
    const size_t o = (size_t)qg * HIDC + s * 32 + kg * 8;
    qhi[s] = *reinterpret_cast<const short8*>(Hhi + o);
    qlo[s] = *reinterpret_cast<const short8*>(Hlo + o);
  }
  const float sqq = SQ[qg];

  unsigned kk[KK2];
  #pragma unroll
  for (int k = 0; k < KK2; ++k) kk[k] = 0xFFFFFFFFu;

  const int jbase = js * JPB2;

  const int srow = 4 * wv + (lane >> 4);
  const int sslt = (lane & 15) ^ (srow & 7);
  auto stage = [&](int buf, int ch) {
    const size_t gofs = (size_t)(jbase + ch * 16 + srow) * HIDC + sslt * 8;
    async_ld16((char*)&As[buf][0][0] + wv * 1024, Hhi + gofs);
    async_ld16((char*)&As[buf][1][0] + wv * 1024, Hlo + gofs);
  };

  stage(0, 0);
  asm volatile("s_waitcnt vmcnt(0)" ::: "memory");
  __syncthreads();

  for (int ch = 0; ch < NCH; ++ch) {
    const int cur = ch & 1;
    if (ch + 1 < NCH) stage(cur ^ 1, ch + 1);

    const int jb = jbase + ch * 16;
    short8 ahi[4], alo[4];
    const int rowb = col * 256;
    #pragma unroll
    for (int s = 0; s < 4; ++s) {
      const int sl = ((s * 4 + kg) ^ (col & 7)) * 16;
      ahi[s] = *(const short8*)((const char*)&As[cur][0][0] + rowb + sl);
      alo[s] = *(const short8*)((const char*)&As[cur][1][0] + rowb + sl);
    }
    f32x4 sqjv = *reinterpret_cast<const f32x4*>(SQ + jb + kg * 4);

    f32x4 acc = {0.f, 0.f, 0.f, 0.f};
    #pragma unroll
    for (int s = 0; s < 4; ++s) {
      acc = mfma16(ahi[s], qhi[s], acc);
      acc = mfma16(ahi[s], qlo[s], acc);
      acc = mfma16(alo[s], qhi[s], acc);
    }
    #pragma unroll
    for (int r = 0; r < 4; ++r) {
      const int jg = jb + kg * 4 + r;
      float d = fmaxf(sqq + sqjv[r] - 2.f * acc[r], 0.f);
      unsigned key = (__float_as_uint(d) & 0xFFFFE000u) | (unsigned)jg;
      if (jg == qg) key = 0xFFFFFFFFu;
      ins_u<KK2>(kk, key);
    }
    asm volatile("s_waitcnt vmcnt(0)" ::: "memory");
    __syncthreads();
  }

  #pragma unroll
  for (int dlt = 16; dlt <= 32; dlt <<= 1) {
    unsigned ok[KK2];
    #pragma unroll
    for (int k = 0; k < KK2; ++k) ok[k] = __shfl_xor((int)kk[k], dlt, 64);
    #pragma unroll
    for (int k = 0; k < KK2; ++k) ins_u<KK2>(kk, ok[k]);
  }
  if (lane < 16) {
    const size_t base = (size_t)qg * CPQ + js * KK2;
    #pragma unroll
    for (int k = 0; k < KK2; ++k) pk2[base + k] = kk[k];   // full keys (sorted)
  }
}

// ---------------------------------------------------------------- rescore: key-merge screen + exact fp32 top-8
// 16-lane group per query (wave = 4 queries, block = 16). Heads-merge the 16
// sorted 8-key lists (16 pops of 4-shuffle min_u32; keys unique) -> key-top-16.
// Lane sl rescores candidate sl exactly (fp32, same formula as R6-passing),
// then 4-round ins_lex butterfly -> exact top-8. Superset: a true top-8
// member outside key-top-16 needs >=16 key-betters but <=7 are truly closer
// => >=9 error-band (~1e-3) flips: negligible.
__global__ __launch_bounds__(256) void knn_rescore_kernel(
    const float* __restrict__ H, const float* __restrict__ SQ,
    const unsigned* __restrict__ pk2, int* __restrict__ idx_out) {
  __shared__ float qrow[16][HIDC + 4];
  const int tid  = threadIdx.x;
  const int lane = tid & 63;
  const int wv   = tid >> 6;
  const int g    = lane >> 4;          // query within wave
  const int sl   = lane & 15;          // list / candidate slot
  const int q0   = blockIdx.x * 16;
  const int qloc = wv * 4 + g;
  const int q    = q0 + qloc;

  for (int u = tid; u < 16 * 32; u += 256) {
    int r = u >> 5, c4 = u & 31;
    *(f32x4*)&qrow[r][c4 * 4] = *(const f32x4*)&H[(size_t)(q0 + r) * HIDC + c4 * 4];
  }
  __syncthreads();

  // load this lane's sorted 8-key list
  unsigned kreg[KK2];
  {
    const unsigned* src = pk2 + (size_t)q * CPQ + sl * KK2;
    uint4 a = *(const uint4*)(src);
    uint4 b = *(const uint4*)(src + 4);
    kreg[0] = a.x; kreg[1] = a.y; kreg[2] = a.z; kreg[3] = a.w;
    kreg[4] = b.x; kreg[5] = b.y; kreg[6] = b.z; kreg[7] = b.w;
  }

  // 16 pops; lane sl keeps pop #sl
  unsigned ckey = 0xFFFFFFFFu;
  #pragma unroll
  for (int t = 0; t < 16; ++t) {
    unsigned m = kreg[0];
    #pragma unroll
    for (int mm = 1; mm <= 8; mm <<= 1) {
      unsigned o = (unsigned)__shfl_xor((int)m, mm, 64);
      m = o < m ? o : m;
    }
    if (t == sl) ckey = m;
    const bool won = (kreg[0] == m);   // keys unique -> exactly one lane
    if (won) {
      #pragma unroll
      for (int p = 0; p < KK2 - 1; ++p) kreg[p] = kreg[p + 1];
      kreg[KK2 - 1] = 0xFFFFFFFFu;
    }
  }
  const int ci = (int)(ckey & 0x1FFFu);

  // exact fp32 rescore of this lane's candidate
  const float* crow = H + (size_t)ci * HIDC;
  float dot = 0.f;
  #pragma unroll 8
  for (int c4 = 0; c4 < HIDC / 4; ++c4) {
    f32x4 qv = *(const f32x4*)&qrow[qloc][c4 * 4];
    f32x4 cv = *(const f32x4*)(crow + c4 * 4);
    dot += qv[0] * cv[0] + qv[1] * cv[1] + qv[2] * cv[2] + qv[3] * cv[3];
  }
  float d = SQ[q] + SQ[ci] - 2.f * dot;

  float kf[KK2]; int ki[KK2];
  kf[0] = d; ki[0] = ci;
  #pragma unroll
  for (int k = 1; k < KK2; ++k) { kf[k] = INFINITY; ki[k] = 0x7fffffff; }
  #pragma unroll
  for (int dlt = 1; dlt <= 8; dlt <<= 1) {
    float of[KK2]; int oi[KK2];
    #pragma unroll
    for (int k = 0; k < KK2; ++k) { of[k] = __shfl_xor(kf[k], dlt, 64); oi[k] = __shfl_xor(ki[k], dlt, 64); }
    #pragma unroll
    for (int k = 0; k < KK2; ++k) ins_lex<KK2>(kf, ki, of[k], oi[k]);
  }
  if (sl == 0) {
    #pragma unroll
    for (int k = 0; k < KK2; ++k) idx_out[(size_t)q * KK2 + k] = ki[k];
  }
}

// ---------------------------------------------------------------- EdgeConv 2 — MFMA, LDS-staged B (R14-validated)
__global__ __launch_bounds__(512) void edgeconv2_kernel(
    const float* __restrict__ PQ, const int* __restrict__ knn,
    const unsigned short* __restrict__ W2Fhi, const unsigned short* __restrict__ W2Flo,
    const float* __restrict__ b2, float* __restrict__ Out) {
  __shared__ __align__(16) unsigned short Ghi[64 * OUTC2];   // 32 KB
  __shared__ __align__(16) unsigned short Glo[64 * OUTC2];   // 32 KB
  __shared__ __align__(16) unsigned short Bs[2][2][8192];    // 64 KB
  const int tid  = threadIdx.x;
  const int lane = tid & 63;
  const int wv   = __builtin_amdgcn_readfirstlane(tid >> 6);
  const int p_base = blockIdx.x * 8;

  {
    const int p   = p_base + wv;
    const int ch0 = lane * 4;
    f32x4 pv = *(const f32x4*)&PQ[(size_t)p * PQC + ch0];
    #pragma unroll
    for (int e = 0; e < KK2; ++e) {
      const int j = knn[p * KK2 + e];
      f32x4 qv = *(const f32x4*)&PQ[(size_t)j * PQC + OUTC2 + ch0];
      unsigned short hb[4], lb[4];
      #pragma unroll
      for (int c = 0; c < 4; ++c) {
        float g = fmaxf(pv[c] + qv[c], 0.f);
        hb[c] = bf16_rn(g);
        float fh = __uint_as_float(((unsigned int)hb[c]) << 16);
        lb[c] = bf16_rn(g - fh);
      }
      const int r   = wv * 8 + e;
      const int off = r * 512 + (((ch0 >> 3) ^ (r & 7)) << 4) + ((ch0 & 7) << 1);
      *(ushort4*)((char*)Ghi + off) = make_ushort4(hb[0], hb[1], hb[2], hb[3]);
      *(ushort4*)((char*)Glo + off) = make_ushort4(lb[0], lb[1], lb[2], lb[3]);
    }
  }

  auto stageB = [&](int buf, int s) {
    #pragma unroll
    for (int i = 0; i < 2; ++i) {
      const size_t go = (size_t)s * 8192 + (size_t)(wv * 2 + i) * 512 + (size_t)lane * 8;
      async_ld16((char*)&Bs[buf][0][0] + (wv * 2 + i) * 1024, W2Fhi + go);
      async_ld16((char*)&Bs[buf][1][0] + (wv * 2 + i) * 1024, W2Flo + go);
    }
  };

  stageB(0, 0);
  asm volatile("s_waitcnt vmcnt(0)" ::: "memory");
  __syncthreads();

  const int col = lane & 15;
  const int kg  = lane >> 4;
  const int mt  = wv & 3;
  const int nh  = wv >> 2;
  const int ar  = mt * 16 + col;
  const int abase = ar * 512;

  f32x4 acc[8];
  #pragma unroll
  for (int n = 0; n < 8; ++n) acc[n] = (f32x4){0.f, 0.f, 0.f, 0.f};

  for (int s = 0; s < 8; ++s) {
    const int cur = s & 1;
    if (s + 1 < 8) stageB(cur ^ 1, s + 1);

    const int asl = (((s * 4 + kg) ^ (ar & 7)) << 4);
    short8 ghi = *(const short8*)((const char*)Ghi + abase + asl);
    short8 glo = *(const short8*)((const char*)Glo + abase + asl);
    #pragma unroll
    for (int n = 0; n < 8; ++n) {
      const int nt = nh * 8 + n;
      const int bo = (nt * 64 + lane) * 16;
      short8 bhi = *(const short8*)((const char*)&Bs[cur][0][0] + bo);
      short8 blo = *(const short8*)((const char*)&Bs[cur][1][0] + bo);
      acc[n] = mfma16(ghi, bhi, acc[n]);
      acc[n] = mfma16(ghi, blo, acc[n]);
      acc[n] = mfma16(glo, bhi, acc[n]);
    }
    asm volatile("s_waitcnt vmcnt(0)" ::: "memory");
    __syncthreads();
  }

  const int pt = p_base + mt * 2 + (kg >> 1);
  #pragma unroll
  for (int n = 0; n < 8; ++n) {
    float m = fmaxf(fmaxf(acc[n][0], acc[n][1]), fmaxf(acc[n][2], acc[n][3]));
    m = fmaxf(m, __shfl_xor(m, 16, 64));
    if ((kg & 1) == 0) {
      const int ncol = nh * 128 + n * 16 + col;
      Out[(size_t)pt * OUTC2 + ncol] = m + b2[ncol];
    }
  }
}

// ---------------------------------------------------------------- launch
extern "C" void kernel_launch(void* const* d_in, const int* in_sizes, int n_in,
                              void* d_out, int out_size, void* d_ws, size_t ws_size,
                              hipStream_t stream) {
  const float* x   = (const float*)d_in[0];
  const float* W1a = (const float*)d_in[1];
  const float* b1a = (const float*)d_in[2];
  const float* W1b = (const float*)d_in[3];
  const float* b1b = (const float*)d_in[4];
  const float* W2a = (const float*)d_in[5];
  const float* b2a = (const float*)d_in[6];
  const float* W2b = (const float*)d_in[7];
  const float* b2b = (const float*)d_in[8];
  float* out = (float*)d_out;

  float* h    = (float*)d_ws;                       // 4 MB
  float* sq2  = h + (size_t)NPTS * HIDC;
  int*   idx1 = (int*)(sq2 + NPTS);
  int*   idx2 = idx1 + (size_t)NPTS * KK1;
  unsigned short* Hhi = (unsigned short*)(idx2 + (size_t)NPTS * KK2);  // 2 MB
  unsigned short* Hlo = Hhi + (size_t)NPTS * HIDC;                     // 2 MB
  unsigned* pk2 = (unsigned*)(Hlo + (size_t)NPTS * HIDC);              // 4 MB
  float* Wc   = (float*)(pk2 + (size_t)NPTS * CPQ); // 256 KB
  float* PQ   = Wc + (size_t)HIDC * PQC;            // 16 MB
  unsigned short* W2Fhi = (unsigned short*)(PQ + (size_t)NPTS * PQC);  // 128 KB
  unsigned short* W2Flo = W2Fhi + (size_t)OUTC2 * OUTC2;               // 128 KB
  // x4 aliases h's first 128KB: knn3 finishes before edgeconv1 writes h.
  float4* x4 = (float4*)h;

  pack_x_kernel<<<(NPTS + 255) / 256, 256, 0, stream>>>(x, x4);
  prep_w1_kernel<<<(HIDC * PQC) / 256, 256, 0, stream>>>(W2a, Wc);
  prep_w2_kernel<<<OUTC2, OUTC2, 0, stream>>>(W2b, W2Fhi, W2Flo);
  knn3_kernel<<<NPTS / 4, 256, 0, stream>>>(x4, idx1);
  edgeconv1_kernel<<<NPTS / 8, 256, 0, stream>>>(x, idx1, W1a, b1a, W1b, b1b,
                                                 h, Hhi, Hlo, sq2);
  gemm_pq_kernel<<<(NPTS / 32) * 8, 256, 0, stream>>>(h, Wc, b2a, PQ);
  knn128_filter_kernel<<<(NPTS / 64) * JSPLIT, 256, 0, stream>>>(Hhi, Hlo, sq2, pk2);
  knn_rescore_kernel<<<NPTS / 16, 256, 0, stream>>>(h, sq2, pk2, idx2);
  edgeconv2_kernel<<<NPTS / 8, 512, 0, stream>>>(PQ, idx2, W2Fhi, W2Flo, b2b, out);
}

// Round 16
// 269.051 us; speedup vs baseline: 1.6334x; 1.1285x over previous
//
#include <hip/hip_runtime.h>
#include <math.h>

constexpr int NPTS  = 8192;
constexpr int HIDC  = 128;
constexpr int OUTC2 = 256;
constexpr int PQC   = 512;
constexpr int KK1   = 16;
constexpr int KK2   = 8;

typedef __attribute__((ext_vector_type(8))) short short8;
typedef __attribute__((ext_vector_type(4))) float f32x4;

__device__ __forceinline__ f32x4 mfma16(short8 a, short8 b, f32x4 c) {
  return __builtin_amdgcn_mfma_f32_16x16x32_bf16(a, b, c, 0, 0, 0);
}

__device__ __forceinline__ void async_ld16(void* lds, const void* g) {
  __builtin_amdgcn_global_load_lds(
      (const __attribute__((address_space(1))) unsigned int*)g,
      (__attribute__((address_space(3))) unsigned int*)lds, 16, 0, 0);
}

// packed-key insert: keys unique (j embedded) -> strict < is exact lex.
template <int K>
__device__ __forceinline__ void ins_u(unsigned (&kk)[K], unsigned v) {
  if (v < kk[K - 1]) {
    kk[K - 1] = v;
    #pragma unroll
    for (int p = K - 1; p > 0; --p) {
      unsigned a = kk[p - 1], b = kk[p];
      kk[p - 1] = a < b ? a : b;
      kk[p]     = a < b ? b : a;
    }
  }
}

// lexicographic (d, idx) insert — exact fp32 merging.
template <int K>
__device__ __forceinline__ void ins_lex(float (&kf)[K], int (&ki)[K], float v, int j) {
  bool ins = (v < kf[K - 1]) || (v == kf[K - 1] && j < ki[K - 1]);
  if (ins) {
    kf[K - 1] = v; ki[K - 1] = j;
    #pragma unroll
    for (int p = K - 1; p > 0; --p) {
      float fa = kf[p - 1], fb = kf[p];
      int   ia = ki[p - 1], ib = ki[p];
      bool sw = (fb < fa) || (fb == fa && ib < ia);
      kf[p - 1] = sw ? fb : fa; ki[p - 1] = sw ? ib : ia;
      kf[p]     = sw ? fa : fb; ki[p]     = sw ? ia : ib;
    }
  }
}

__device__ __forceinline__ unsigned short bf16_rn(float x) {
  unsigned int u = __float_as_uint(x);
  unsigned int r = u + 0x7fffu + ((u >> 16) & 1u);
  return (unsigned short)(r >> 16);
}

// ---------------------------------------------------------------- pack x
__global__ void pack_x_kernel(const float* __restrict__ x, float4* __restrict__ x4) {
  int i = blockIdx.x * blockDim.x + threadIdx.x;
  if (i < NPTS) {
    float a = x[3 * i], b = x[3 * i + 1], c = x[3 * i + 2];
    x4[i] = make_float4(a, b, c, a * a + b * b + c * c);
  }
}

// ---------------------------------------------------------------- Wc = [Wl-Wh | Wh] -> fragment-major bf16 hi/lo
// WcF[((s*32 + nt)*64 + (kg*16+ct))*8 + e], k = s*32+kg*8+e, c = nt*16+ct.
__global__ void prep_w1f_kernel(const float* __restrict__ W1,
                                unsigned short* __restrict__ WcFhi,
                                unsigned short* __restrict__ WcFlo) {
  int idx = blockIdx.x * 256 + threadIdx.x;    // 128*512
  int k = idx >> 9, c = idx & 511;
  float wh = W1[(size_t)(HIDC + k) * OUTC2 + (c & 255)];
  float w = (c < OUTC2) ? (W1[(size_t)k * OUTC2 + c] - wh) : wh;
  unsigned short hi = bf16_rn(w);
  float fh = __uint_as_float(((unsigned int)hi) << 16);
  unsigned short lo = bf16_rn(w - fh);
  const int nt = c >> 4, ct = c & 15;
  const int s = k >> 5, kg = (k >> 3) & 3, e = k & 7;
  const size_t fidx = ((size_t)(s * 32 + nt) * 64 + (kg * 16 + ct)) * 8 + e;
  WcFhi[fidx] = hi;
  WcFlo[fidx] = lo;
}

// ---------------------------------------------------------------- W1b (128x128) -> fragment-major bf16 hi/lo
__global__ void prep_w1b_kernel(const float* __restrict__ W,
                                unsigned short* __restrict__ Fhi,
                                unsigned short* __restrict__ Flo) {
  const int c = blockIdx.x;   // 0..127 out ch
  const int k = threadIdx.x;  // 0..127
  float w = W[(size_t)k * HIDC + c];
  unsigned short hi = bf16_rn(w);
  float fh = __uint_as_float(((unsigned int)hi) << 16);
  unsigned short lo = bf16_rn(w - fh);
  const int nt = c >> 4, ct = c & 15;
  const int s = k >> 5, kg = (k >> 3) & 3, e = k & 7;
  const size_t idx = ((size_t)(s * 8 + nt) * 64 + (kg * 16 + ct)) * 8 + e;
  Fhi[idx] = hi;
  Flo[idx] = lo;
}

// ---------------------------------------------------------------- W2 (256x256) -> fragment-major bf16 hi/lo
__global__ void prep_w2_kernel(const float* __restrict__ W2,
                               unsigned short* __restrict__ W2Fhi,
                               unsigned short* __restrict__ W2Flo) {
  const int c = blockIdx.x;      // out channel 0..255
  const int k = threadIdx.x;     // inner dim   0..255
  float w = W2[(size_t)k * OUTC2 + c];
  unsigned short hi = bf16_rn(w);
  float fh = __uint_as_float(((unsigned int)hi) << 16);
  unsigned short lo = bf16_rn(w - fh);
  const int nt = c >> 4, ct = c & 15;
  const int s  = k >> 5, kg = (k >> 3) & 3, e = k & 7;
  const int lane = kg * 16 + ct;
  const size_t idx = ((size_t)(s * 16 + nt) * 64 + lane) * 8 + e;
  W2Fhi[idx] = hi;
  W2Flo[idx] = lo;
}

// ---------------------------------------------------------------- KNN1 (C=3, K=16) — unchanged (R11-validated)
__global__ __launch_bounds__(256) void knn3_kernel(const float4* __restrict__ X4,
                                                   int* __restrict__ idx_out) {
  const int tid  = threadIdx.x;
  const int lane = tid & 63;
  const int wv   = __builtin_amdgcn_readfirstlane(tid >> 6);
  const int q    = blockIdx.x * 4 + wv;

  const float4 qv = X4[q];

  unsigned kk[KK2];
  #pragma unroll
  for (int k = 0; k < KK2; ++k) kk[k] = 0xFFFFFFFFu;

  for (int c = 0; c < NPTS / 64; ++c) {
    const int j = c * 64 + lane;
    float4 pj = X4[j];
    float d = fmaxf(qv.w + pj.w - 2.f * (qv.x * pj.x + qv.y * pj.y + qv.z * pj.z), 0.f);
    unsigned key = (__float_as_uint(d) & 0xFFFFE000u) | (unsigned)j;
    if (j == q) key = 0xFFFFFFFFu;
    ins_u<KK2>(kk, key);
  }

  float kf[KK2]; int kj[KK2];
  #pragma unroll
  for (int k = 0; k < KK2; ++k) { kf[k] = INFINITY; kj[k] = 0x7fffffff; }
  #pragma unroll
  for (int k = 0; k < KK2; ++k) {
    int j = (int)(kk[k] & 0x1FFFu);
    float4 pj = X4[j];
    float d = qv.w + pj.w - 2.f * (qv.x * pj.x + qv.y * pj.y + qv.z * pj.z);
    if (kk[k] == 0xFFFFFFFFu) { d = INFINITY; j = 0x7fffffff; }
    ins_lex<KK2>(kf, kj, d, j);
  }

  #pragma unroll
  for (int k = 0; k < KK1; ++k) {
    float mf = kf[0]; int mj = kj[0];
    #pragma unroll
    for (int m = 1; m <= 32; m <<= 1) {
      float of = __shfl_xor(mf, m, 64);
      int   oj = __shfl_xor(mj, m, 64);
      bool g = (of < mf) || (of == mf && oj < mj);
      mf = g ? of : mf; mj = g ? oj : mj;
    }
    const bool won = (kf[0] == mf) && (kj[0] == mj);
    if (won) {
      idx_out[(size_t)q * KK1 + k] = mj;
      #pragma unroll
      for (int p = 0; p < KK2 - 1; ++p) { kf[p] = kf[p + 1]; kj[p] = kj[p + 1]; }
      kf[KK2 - 1] = INFINITY; kj[KK2 - 1] = 0x7fffffff;
    }
  }
}

// ---------------------------------------------------------------- EdgeConv 1 — MFMA stage-2
// Block = 8 points, 512 thr (8 waves). Wave wv owns point p_base+wv:
// stage 1 computes 16 edge features (6->128 MLP) as bf16 hi/lo into
// swizzled LDS G rows wv*16+e (same swizzle family as ec2's G — validated).
// Stage 2: D(16 edges x 128 ch) = G_tile @ W1b via 3-term bf16x2 MFMA;
// B slices (8KB hi + 8KB lo) double-buffered via per-lane gload_lds from
// fragment-major W1bF (R14-validated pattern). Epilogue: max over the 16
// edge rows (4-reg max + shfl_xor 16,32) + b2 -> H fp32 + bf16 hi/lo + SQ2.
__global__ __launch_bounds__(512) void edgeconv1_kernel(
    const float* __restrict__ X, const int* __restrict__ knn,
    const float* __restrict__ W1, const float* __restrict__ b1,
    const unsigned short* __restrict__ W1bFhi, const unsigned short* __restrict__ W1bFlo,
    const float* __restrict__ b2,
    float* __restrict__ H, unsigned short* __restrict__ Hhi,
    unsigned short* __restrict__ Hlo, float* __restrict__ SQ2) {
  __shared__ __align__(16) unsigned short Ghi[128 * HIDC];  // 32 KB
  __shared__ __align__(16) unsigned short Glo[128 * HIDC];  // 32 KB
  __shared__ __align__(16) unsigned short Bs[2][2][4096];   // 32 KB
  __shared__ float xjs[8][KK1][3];
  __shared__ float xis[8][3];
  const int tid  = threadIdx.x;
  const int lane = tid & 63;
  const int wv   = __builtin_amdgcn_readfirstlane(tid >> 6);
  const int p    = blockIdx.x * 8 + wv;

  if (lane < KK1) {
    int j = knn[p * KK1 + lane];
    xjs[wv][lane][0] = X[3 * j]; xjs[wv][lane][1] = X[3 * j + 1]; xjs[wv][lane][2] = X[3 * j + 2];
  } else if (lane < KK1 + 3) {
    xis[wv][lane - KK1] = X[3 * p + lane - KK1];
  }
  __syncthreads();

  // ---- stage 1: edge MLP -> swizzled bf16 hi/lo G (thread = 2 channels)
  {
    const int ch0 = lane * 2;
    float2 w1r[6];
    #pragma unroll
    for (int c = 0; c < 6; ++c)
      w1r[c] = make_float2(W1[c * HIDC + ch0], W1[c * HIDC + ch0 + 1]);
    const float2 b1v = make_float2(b1[ch0], b1[ch0 + 1]);
    const float xi0 = xis[wv][0], xi1 = xis[wv][1], xi2 = xis[wv][2];
    const float base0 = b1v.x + xi0 * w1r[0].x + xi1 * w1r[1].x + xi2 * w1r[2].x;
    const float base1 = b1v.y + xi0 * w1r[0].y + xi1 * w1r[1].y + xi2 * w1r[2].y;
    #pragma unroll
    for (int e = 0; e < KK1; ++e) {
      float dx = xjs[wv][e][0] - xi0, dy = xjs[wv][e][1] - xi1, dz = xjs[wv][e][2] - xi2;
      float v0 = fmaxf(base0 + dx * w1r[3].x + dy * w1r[4].x + dz * w1r[5].x, 0.f);
      float v1 = fmaxf(base1 + dx * w1r[3].y + dy * w1r[4].y + dz * w1r[5].y, 0.f);
      unsigned short h0 = bf16_rn(v0), h1s = bf16_rn(v1);
      unsigned short l0 = bf16_rn(v0 - __uint_as_float(((unsigned)h0) << 16));
      unsigned short l1 = bf16_rn(v1 - __uint_as_float(((unsigned)h1s) << 16));
      const int r   = wv * 16 + e;
      const int off = r * 256 + (((ch0 >> 3) ^ (r & 7)) << 4) + ((ch0 & 7) << 1);
      *(ushort2*)((char*)Ghi + off) = make_ushort2(h0, h1s);
      *(ushort2*)((char*)Glo + off) = make_ushort2(l0, l1);
    }
  }

  auto stageB = [&](int buf, int s) {
    const size_t go = (size_t)s * 4096 + (size_t)wv * 512 + (size_t)lane * 8;
    async_ld16((char*)&Bs[buf][0][0] + wv * 1024, W1bFhi + go);
    async_ld16((char*)&Bs[buf][1][0] + wv * 1024, W1bFlo + go);
  };

  stageB(0, 0);
  asm volatile("s_waitcnt vmcnt(0)" ::: "memory");
  __syncthreads();

  // ---- stage 2
  const int col = lane & 15;
  const int kg  = lane >> 4;
  const int ar  = wv * 16 + col;
  const int abase = ar * 256;

  f32x4 acc[8];
  #pragma unroll
  for (int n = 0; n < 8; ++n) acc[n] = (f32x4){0.f, 0.f, 0.f, 0.f};

  for (int s = 0; s < 4; ++s) {
    const int cur = s & 1;
    if (s + 1 < 4) stageB(cur ^ 1, s + 1);
    const int asl = (((s * 4 + kg) ^ (ar & 7)) << 4);
    short8 ghi = *(const short8*)((const char*)Ghi + abase + asl);
    short8 glo = *(const short8*)((const char*)Glo + abase + asl);
    #pragma unroll
    for (int n = 0; n < 8; ++n) {
      const int bo = (n * 64 + lane) * 16;
      short8 bhi = *(const short8*)((const char*)&Bs[cur][0][0] + bo);
      short8 blo = *(const short8*)((const char*)&Bs[cur][1][0] + bo);
      acc[n] = mfma16(ghi, bhi, acc[n]);
      acc[n] = mfma16(ghi, blo, acc[n]);
      acc[n] = mfma16(glo, bhi, acc[n]);
    }
    asm volatile("s_waitcnt vmcnt(0)" ::: "memory");
    __syncthreads();
  }

  // ---- epilogue: max over 16 edge rows; emit H, Hhi/Hlo, SQ2
  float sq = 0.f;
  float hv[8];
  #pragma unroll
  for (int n = 0; n < 8; ++n) {
    float m = fmaxf(fmaxf(acc[n][0], acc[n][1]), fmaxf(acc[n][2], acc[n][3]));
    m = fmaxf(m, __shfl_xor(m, 16, 64));
    m = fmaxf(m, __shfl_xor(m, 32, 64));
    m += b2[n * 16 + col];
    hv[n] = m;
    sq += m * m;
  }
  if (kg == 0) {
    #pragma unroll
    for (int n = 0; n < 8; ++n) {
      const int ch = n * 16 + col;
      H[(size_t)p * HIDC + ch] = hv[n];
      unsigned short hb = bf16_rn(hv[n]);
      float fh = __uint_as_float(((unsigned)hb) << 16);
      Hhi[(size_t)p * HIDC + ch] = hb;
      Hlo[(size_t)p * HIDC + ch] = bf16_rn(hv[n] - fh);
    }
  }
  #pragma unroll
  for (int m2 = 1; m2 <= 8; m2 <<= 1) sq += __shfl_xor(sq, m2, 64);
  if (lane == 0) SQ2[p] = sq;
}

// ---------------------------------------------------------------- PQ = H @ Wc via MFMA (bf16x2, 3 terms)
// Grid: (8192/64) m-blocks x 2 n-splits. Block = 64 H rows x 256 PQ cols,
// 512 thr (wave = m-tile (wv&3) x n-half (wv>>2)). A = Hhi/Hlo staged
// swizzled once; B slices (16KB hi + 16KB lo) double-buffered from WcF.
__global__ __launch_bounds__(512) void gemm_pq_kernel(
    const unsigned short* __restrict__ Hhi, const unsigned short* __restrict__ Hlo,
    const unsigned short* __restrict__ WcFhi, const unsigned short* __restrict__ WcFlo,
    const float* __restrict__ b1, float* __restrict__ PQ) {
  __shared__ __align__(16) unsigned short Ahi[64 * HIDC];   // 16 KB
  __shared__ __align__(16) unsigned short Alo[64 * HIDC];   // 16 KB
  __shared__ __align__(16) unsigned short Bsl[2][2][8192];  // 64 KB
  const int tid  = threadIdx.x;
  const int lane = tid & 63;
  const int wv   = __builtin_amdgcn_readfirstlane(tid >> 6);
  const int mb   = blockIdx.x >> 1;
  const int ns   = blockIdx.x & 1;
  const int r0   = mb * 64;

  #pragma unroll
  for (int i = 0; i < 2; ++i) {
    const int srow = wv * 8 + i * 4 + (lane >> 4);
    const int sslt = (lane & 15) ^ (srow & 7);
    const size_t go = (size_t)(r0 + srow) * HIDC + sslt * 8;
    async_ld16((char*)Ahi + (wv * 8 + i * 4) * 256, Hhi + go);
    async_ld16((char*)Alo + (wv * 8 + i * 4) * 256, Hlo + go);
  }
  auto stageB = [&](int buf, int s) {
    #pragma unroll
    for (int i = 0; i < 2; ++i) {
      const size_t go = (size_t)(s * 32 + ns * 16) * 512 + (size_t)wv * 1024 + i * 512 + lane * 8;
      async_ld16((char*)&Bsl[buf][0][0] + wv * 2048 + i * 1024, WcFhi + go);
      async_ld16((char*)&Bsl[buf][1][0] + wv * 2048 + i * 1024, WcFlo + go);
    }
  };
  stageB(0, 0);
  asm volatile("s_waitcnt vmcnt(0)" ::: "memory");
  __syncthreads();

  const int col = lane & 15;
  const int kg  = lane >> 4;
  const int mt  = wv & 3;
  const int nh  = wv >> 2;
  const int ar  = mt * 16 + col;
  const int abase = ar * 256;

  f32x4 acc[8];
  #pragma unroll
  for (int n = 0; n < 8; ++n) acc[n] = (f32x4){0.f, 0.f, 0.f, 0.f};

  for (int s = 0; s < 4; ++s) {
    const int cur = s & 1;
    if (s + 1 < 4) stageB(cur ^ 1, s + 1);
    const int asl = (((s * 4 + kg) ^ (ar & 7)) << 4);
    short8 ahi8 = *(const short8*)((const char*)Ahi + abase + asl);
    short8 alo8 = *(const short8*)((const char*)Alo + abase + asl);
    #pragma unroll
    for (int n = 0; n < 8; ++n) {
      const int ntl = nh * 8 + n;
      const int bo = (ntl * 64 + lane) * 16;
      short8 bhi = *(const short8*)((const char*)&Bsl[cur][0][0] + bo);
      short8 blo = *(const short8*)((const char*)&Bsl[cur][1][0] + bo);
      acc[n] = mfma16(ahi8, bhi, acc[n]);
      acc[n] = mfma16(ahi8, blo, acc[n]);
      acc[n] = mfma16(alo8, bhi, acc[n]);
    }
    asm volatile("s_waitcnt vmcnt(0)" ::: "memory");
    __syncthreads();
  }

  // epilogue: D row = kg*4+r (H row within m-tile), col = lane&15
  #pragma unroll
  for (int n = 0; n < 8; ++n) {
    const int cg = ns * 256 + (nh * 8 + n) * 16 + col;
    const float bb = (ns == 0) ? b1[cg] : 0.f;
    #pragma unroll
    for (int r = 0; r < 4; ++r) {
      const int row = r0 + mt * 16 + kg * 4 + r;
      PQ[(size_t)row * PQC + cg] = acc[n][r] + bb;
    }
  }
}

// ---------------------------------------------------------------- KNN2 filter (unchanged from R15)
constexpr int JSPLIT = 16;
constexpr int JPB2   = NPTS / JSPLIT;
constexpr int NCH    = JPB2 / 16;
constexpr int CPQ    = JSPLIT * KK2;   // 128 keys per query

__global__ __launch_bounds__(256) void knn128_filter_kernel(
    const unsigned short* __restrict__ Hhi, const unsigned short* __restrict__ Hlo,
    const float* __restrict__ SQ, unsigned* __restrict__ pk2) {
  __shared__ __align__(16) unsigned short As[2][2][16 * HIDC];
  const int tid  = threadIdx.x;
  const int lane = tid & 63;
  const int wv   = __builtin_amdgcn_readfirstlane(tid >> 6);
  const int qb   = blockIdx.x >> 4;
  const int js   = blockIdx.x & 15;
  const int col  = lane & 15;
  const int kg   = lane >> 4;
  const int qg   = qb * 64 + wv * 16 + col;

  short8 qhi[4], qlo[4];
  #pragma unroll
  for (int s = 0; s < 4; ++s) {
    const size_t o = (size_t)qg * HIDC + s * 32 + kg * 8;
    qhi[s] = *reinterpret_cast<const short8*>(Hhi + o);
    qlo[s] = *reinterpret_cast<const short8*>(Hlo + o);
  }
  const float sqq = SQ[qg];

  unsigned kk[KK2];
  #pragma unroll
  for (int k = 0; k < KK2; ++k) kk[k] = 0xFFFFFFFFu;

  const int jbase = js * JPB2;

  const int srow = 4 * wv + (lane >> 4);
  const int sslt = (lane & 15) ^ (srow & 7);
  auto stage = [&](int buf, int ch) {
    const size_t gofs = (size_t)(jbase + ch * 16 + srow) * HIDC + sslt * 8;
    async_ld16((char*)&As[buf][0][0] + wv * 1024, Hhi + gofs);
    async_ld16((char*)&As[buf][1][0] + wv * 1024, Hlo + gofs);
  };

  stage(0, 0);
  asm volatile("s_waitcnt vmcnt(0)" ::: "memory");
  __syncthreads();

  for (int ch = 0; ch < NCH; ++ch) {
    const int cur = ch & 1;
    if (ch + 1 < NCH) stage(cur ^ 1, ch + 1);

    const int jb = jbase + ch * 16;
    short8 ahi[4], alo[4];
    const int rowb = col * 256;
    #pragma unroll
    for (int s = 0; s < 4; ++s) {
      const int sl = ((s * 4 + kg) ^ (col & 7)) * 16;
      ahi[s] = *(const short8*)((const char*)&As[cur][0][0] + rowb + sl);
      alo[s] = *(const short8*)((const char*)&As[cur][1][0] + rowb + sl);
    }
    f32x4 sqjv = *reinterpret_cast<const f32x4*>(SQ + jb + kg * 4);

    f32x4 acc = {0.f, 0.f, 0.f, 0.f};
    #pragma unroll
    for (int s = 0; s < 4; ++s) {
      acc = mfma16(ahi[s], qhi[s], acc);
      acc = mfma16(ahi[s], qlo[s], acc);
      acc = mfma16(alo[s], qhi[s], acc);
    }
    #pragma unroll
    for (int r = 0; r < 4; ++r) {
      const int jg = jb + kg * 4 + r;
      float d = fmaxf(sqq + sqjv[r] - 2.f * acc[r], 0.f);
      unsigned key = (__float_as_uint(d) & 0xFFFFE000u) | (unsigned)jg;
      if (jg == qg) key = 0xFFFFFFFFu;
      ins_u<KK2>(kk, key);
    }
    asm volatile("s_waitcnt vmcnt(0)" ::: "memory");
    __syncthreads();
  }

  #pragma unroll
  for (int dlt = 16; dlt <= 32; dlt <<= 1) {
    unsigned ok[KK2];
    #pragma unroll
    for (int k = 0; k < KK2; ++k) ok[k] = __shfl_xor((int)kk[k], dlt, 64);
    #pragma unroll
    for (int k = 0; k < KK2; ++k) ins_u<KK2>(kk, ok[k]);
  }
  if (lane < 16) {
    const size_t base = (size_t)qg * CPQ + js * KK2;
    #pragma unroll
    for (int k = 0; k < KK2; ++k) pk2[base + k] = kk[k];
  }
}

// ---------------------------------------------------------------- rescore (unchanged from R15)
__global__ __launch_bounds__(256) void knn_rescore_kernel(
    const float* __restrict__ H, const float* __restrict__ SQ,
    const unsigned* __restrict__ pk2, int* __restrict__ idx_out) {
  __shared__ float qrow[16][HIDC + 4];
  const int tid  = threadIdx.x;
  const int lane = tid & 63;
  const int wv   = tid >> 6;
  const int g    = lane >> 4;
  const int sl   = lane & 15;
  const int q0   = blockIdx.x * 16;
  const int qloc = wv * 4 + g;
  const int q    = q0 + qloc;

  for (int u = tid; u < 16 * 32; u += 256) {
    int r = u >> 5, c4 = u & 31;
    *(f32x4*)&qrow[r][c4 * 4] = *(const f32x4*)&H[(size_t)(q0 + r) * HIDC + c4 * 4];
  }
  __syncthreads();

  unsigned kreg[KK2];
  {
    const unsigned* src = pk2 + (size_t)q * CPQ + sl * KK2;
    uint4 a = *(const uint4*)(src);
    uint4 b = *(const uint4*)(src + 4);
    kreg[0] = a.x; kreg[1] = a.y; kreg[2] = a.z; kreg[3] = a.w;
    kreg[4] = b.x; kreg[5] = b.y; kreg[6] = b.z; kreg[7] = b.w;
  }

  unsigned ckey = 0xFFFFFFFFu;
  #pragma unroll
  for (int t = 0; t < 16; ++t) {
    unsigned m = kreg[0];
    #pragma unroll
    for (int mm = 1; mm <= 8; mm <<= 1) {
      unsigned o = (unsigned)__shfl_xor((int)m, mm, 64);
      m = o < m ? o : m;
    }
    if (t == sl) ckey = m;
    const bool won = (kreg[0] == m);
    if (won) {
      #pragma unroll
      for (int p = 0; p < KK2 - 1; ++p) kreg[p] = kreg[p + 1];
      kreg[KK2 - 1] = 0xFFFFFFFFu;
    }
  }
  const int ci = (int)(ckey & 0x1FFFu);

  const float* crow = H + (size_t)ci * HIDC;
  float dot = 0.f;
  #pragma unroll 8
  for (int c4 = 0; c4 < HIDC / 4; ++c4) {
    f32x4 qv = *(const f32x4*)&qrow[qloc][c4 * 4];
    f32x4 cv = *(const f32x4*)(crow + c4 * 4);
    dot += qv[0] * cv[0] + qv[1] * cv[1] + qv[2] * cv[2] + qv[3] * cv[3];
  }
  float d = SQ[q] + SQ[ci] - 2.f * dot;

  float kf[KK2]; int ki[KK2];
  kf[0] = d; ki[0] = ci;
  #pragma unroll
  for (int k = 1; k < KK2; ++k) { kf[k] = INFINITY; ki[k] = 0x7fffffff; }
  #pragma unroll
  for (int dlt = 1; dlt <= 8; dlt <<= 1) {
    float of[KK2]; int oi[KK2];
    #pragma unroll
    for (int k = 0; k < KK2; ++k) { of[k] = __shfl_xor(kf[k], dlt, 64); oi[k] = __shfl_xor(ki[k], dlt, 64); }
    #pragma unroll
    for (int k = 0; k < KK2; ++k) ins_lex<KK2>(kf, ki, of[k], oi[k]);
  }
  if (sl == 0) {
    #pragma unroll
    for (int k = 0; k < KK2; ++k) idx_out[(size_t)q * KK2 + k] = ki[k];
  }
}

// ---------------------------------------------------------------- EdgeConv 2 — MFMA, LDS-staged B (R14-validated)
__global__ __launch_bounds__(512) void edgeconv2_kernel(
    const float* __restrict__ PQ, const int* __restrict__ knn,
    const unsigned short* __restrict__ W2Fhi, const unsigned short* __restrict__ W2Flo,
    const float* __restrict__ b2, float* __restrict__ Out) {
  __shared__ __align__(16) unsigned short Ghi[64 * OUTC2];   // 32 KB
  __shared__ __align__(16) unsigned short Glo[64 * OUTC2];   // 32 KB
  __shared__ __align__(16) unsigned short Bs[2][2][8192];    // 64 KB
  const int tid  = threadIdx.x;
  const int lane = tid & 63;
  const int wv   = __builtin_amdgcn_readfirstlane(tid >> 6);
  const int p_base = blockIdx.x * 8;

  {
    const int p   = p_base + wv;
    const int ch0 = lane * 4;
    f32x4 pv = *(const f32x4*)&PQ[(size_t)p * PQC + ch0];
    #pragma unroll
    for (int e = 0; e < KK2; ++e) {
      const int j = knn[p * KK2 + e];
      f32x4 qv = *(const f32x4*)&PQ[(size_t)j * PQC + OUTC2 + ch0];
      unsigned short hb[4], lb[4];
      #pragma unroll
      for (int c = 0; c < 4; ++c) {
        float g = fmaxf(pv[c] + qv[c], 0.f);
        hb[c] = bf16_rn(g);
        float fh = __uint_as_float(((unsigned int)hb[c]) << 16);
        lb[c] = bf16_rn(g - fh);
      }
      const int r   = wv * 8 + e;
      const int off = r * 512 + (((ch0 >> 3) ^ (r & 7)) << 4) + ((ch0 & 7) << 1);
      *(ushort4*)((char*)Ghi + off) = make_ushort4(hb[0], hb[1], hb[2], hb[3]);
      *(ushort4*)((char*)Glo + off) = make_ushort4(lb[0], lb[1], lb[2], lb[3]);
    }
  }

  auto stageB = [&](int buf, int s) {
    #pragma unroll
    for (int i = 0; i < 2; ++i) {
      const size_t go = (size_t)s * 8192 + (size_t)(wv * 2 + i) * 512 + (size_t)lane * 8;
      async_ld16((char*)&Bs[buf][0][0] + (wv * 2 + i) * 1024, W2Fhi + go);
      async_ld16((char*)&Bs[buf][1][0] + (wv * 2 + i) * 1024, W2Flo + go);
    }
  };

  stageB(0, 0);
  asm volatile("s_waitcnt vmcnt(0)" ::: "memory");
  __syncthreads();

  const int col = lane & 15;
  const int kg  = lane >> 4;
  const int mt  = wv & 3;
  const int nh  = wv >> 2;
  const int ar  = mt * 16 + col;
  const int abase = ar * 512;

  f32x4 acc[8];
  #pragma unroll
  for (int n = 0; n < 8; ++n) acc[n] = (f32x4){0.f, 0.f, 0.f, 0.f};

  for (int s = 0; s < 8; ++s) {
    const int cur = s & 1;
    if (s + 1 < 8) stageB(cur ^ 1, s + 1);

    const int asl = (((s * 4 + kg) ^ (ar & 7)) << 4);
    short8 ghi = *(const short8*)((const char*)Ghi + abase + asl);
    short8 glo = *(const short8*)((const char*)Glo + abase + asl);
    #pragma unroll
    for (int n = 0; n < 8; ++n) {
      const int nt = nh * 8 + n;
      const int bo = (nt * 64 + lane) * 16;
      short8 bhi = *(const short8*)((const char*)&Bs[cur][0][0] + bo);
      short8 blo = *(const short8*)((const char*)&Bs[cur][1][0] + bo);
      acc[n] = mfma16(ghi, bhi, acc[n]);
      acc[n] = mfma16(ghi, blo, acc[n]);
      acc[n] = mfma16(glo, bhi, acc[n]);
    }
    asm volatile("s_waitcnt vmcnt(0)" ::: "memory");
    __syncthreads();
  }

  const int pt = p_base + mt * 2 + (kg >> 1);
  #pragma unroll
  for (int n = 0; n < 8; ++n) {
    float m = fmaxf(fmaxf(acc[n][0], acc[n][1]), fmaxf(acc[n][2], acc[n][3]));
    m = fmaxf(m, __shfl_xor(m, 16, 64));
    if ((kg & 1) == 0) {
      const int ncol = nh * 128 + n * 16 + col;
      Out[(size_t)pt * OUTC2 + ncol] = m + b2[ncol];
    }
  }
}

// ---------------------------------------------------------------- launch
extern "C" void kernel_launch(void* const* d_in, const int* in_sizes, int n_in,
                              void* d_out, int out_size, void* d_ws, size_t ws_size,
                              hipStream_t stream) {
  const float* x   = (const float*)d_in[0];
  const float* W1a = (const float*)d_in[1];
  const float* b1a = (const float*)d_in[2];
  const float* W1b = (const float*)d_in[3];
  const float* b1b = (const float*)d_in[4];
  const float* W2a = (const float*)d_in[5];
  const float* b2a = (const float*)d_in[6];
  const float* W2b = (const float*)d_in[7];
  const float* b2b = (const float*)d_in[8];
  float* out = (float*)d_out;

  float* h    = (float*)d_ws;                       // 4 MB
  float* sq2  = h + (size_t)NPTS * HIDC;
  int*   idx1 = (int*)(sq2 + NPTS);
  int*   idx2 = idx1 + (size_t)NPTS * KK1;
  unsigned short* Hhi = (unsigned short*)(idx2 + (size_t)NPTS * KK2);  // 2 MB
  unsigned short* Hlo = Hhi + (size_t)NPTS * HIDC;                     // 2 MB
  unsigned* pk2 = (unsigned*)(Hlo + (size_t)NPTS * HIDC);              // 4 MB
  float* PQ   = (float*)(pk2 + (size_t)NPTS * CPQ); // 16 MB
  unsigned short* W2Fhi = (unsigned short*)(PQ + (size_t)NPTS * PQC);  // 128 KB
  unsigned short* W2Flo = W2Fhi + (size_t)OUTC2 * OUTC2;               // 128 KB
  unsigned short* WcFhi = W2Flo + (size_t)OUTC2 * OUTC2;               // 128 KB
  unsigned short* WcFlo = WcFhi + (size_t)HIDC * PQC;                  // 128 KB
  unsigned short* W1bFhi = WcFlo + (size_t)HIDC * PQC;                 // 32 KB
  unsigned short* W1bFlo = W1bFhi + (size_t)HIDC * HIDC;               // 32 KB
  // x4 aliases h's first 128KB: knn3 finishes before edgeconv1 writes h.
  float4* x4 = (float4*)h;

  pack_x_kernel<<<(NPTS + 255) / 256, 256, 0, stream>>>(x, x4);
  prep_w1f_kernel<<<(HIDC * PQC) / 256, 256, 0, stream>>>(W2a, WcFhi, WcFlo);
  prep_w1b_kernel<<<HIDC, HIDC, 0, stream>>>(W1b, W1bFhi, W1bFlo);
  prep_w2_kernel<<<OUTC2, OUTC2, 0, stream>>>(W2b, W2Fhi, W2Flo);
  knn3_kernel<<<NPTS / 4, 256, 0, stream>>>(x4, idx1);
  edgeconv1_kernel<<<NPTS / 8, 512, 0, stream>>>(x, idx1, W1a, b1a,
                                                 W1bFhi, W1bFlo, b1b,
                                                 h, Hhi, Hlo, sq2);
  gemm_pq_kernel<<<(NPTS / 64) * 2, 512, 0, stream>>>(Hhi, Hlo, WcFhi, WcFlo, b2a, PQ);
  knn128_filter_kernel<<<(NPTS / 64) * JSPLIT, 256, 0, stream>>>(Hhi, Hlo, sq2, pk2);
  knn_rescore_kernel<<<NPTS / 16, 256, 0, stream>>>(h, sq2, pk2, idx2);
  edgeconv2_kernel<<<NPTS / 8, 512, 0, stream>>>(PQ, idx2, W2Fhi, W2Flo, b2b, out);
}

// Round 17
// 263.071 us; speedup vs baseline: 1.6705x; 1.0227x over previous
//
#include <hip/hip_runtime.h>
#include <math.h>

constexpr int NPTS  = 8192;
constexpr int HIDC  = 128;
constexpr int OUTC2 = 256;
constexpr int PQC   = 512;
constexpr int KK1   = 16;
constexpr int KK2   = 8;

typedef __attribute__((ext_vector_type(8))) short short8;
typedef __attribute__((ext_vector_type(4))) float f32x4;

__device__ __forceinline__ f32x4 mfma16(short8 a, short8 b, f32x4 c) {
  return __builtin_amdgcn_mfma_f32_16x16x32_bf16(a, b, c, 0, 0, 0);
}

__device__ __forceinline__ void async_ld16(void* lds, const void* g) {
  __builtin_amdgcn_global_load_lds(
      (const __attribute__((address_space(1))) unsigned int*)g,
      (__attribute__((address_space(3))) unsigned int*)lds, 16, 0, 0);
}

#define CEU(a, b) { unsigned _t = (a) < (b) ? (a) : (b); (b) = (a) < (b) ? (b) : (a); (a) = _t; }

// Batch top-8 update: kk[0..7] sorted asc; b0<=b1<=b2<=b3 sorted new keys.
// Bitonic halver (S = [kk asc | INF x4, b3,b2,b1,b0 desc] is bitonic; the
// per-position min of its halves = exact smallest-8, itself bitonic), then
// a 12-CE bitonic merge re-sorts. Keys unique -> exact lex top-8 SET.
__device__ __forceinline__ void topk8_batch4(unsigned (&kk)[KK2],
                                             unsigned b0, unsigned b1,
                                             unsigned b2, unsigned b3) {
  CEU(b0, b1); CEU(b2, b3); CEU(b0, b2); CEU(b1, b3); CEU(b1, b2);
  if (b0 < kk[7]) {
    kk[4] = kk[4] < b3 ? kk[4] : b3;
    kk[5] = kk[5] < b2 ? kk[5] : b2;
    kk[6] = kk[6] < b1 ? kk[6] : b1;
    kk[7] = kk[7] < b0 ? kk[7] : b0;
    CEU(kk[0], kk[4]); CEU(kk[1], kk[5]); CEU(kk[2], kk[6]); CEU(kk[3], kk[7]);
    CEU(kk[0], kk[2]); CEU(kk[1], kk[3]); CEU(kk[4], kk[6]); CEU(kk[5], kk[7]);
    CEU(kk[0], kk[1]); CEU(kk[2], kk[3]); CEU(kk[4], kk[5]); CEU(kk[6], kk[7]);
  }
}

// lexicographic (d, idx) insert — exact fp32 merging.
template <int K>
__device__ __forceinline__ void ins_lex(float (&kf)[K], int (&ki)[K], float v, int j) {
  bool ins = (v < kf[K - 1]) || (v == kf[K - 1] && j < ki[K - 1]);
  if (ins) {
    kf[K - 1] = v; ki[K - 1] = j;
    #pragma unroll
    for (int p = K - 1; p > 0; --p) {
      float fa = kf[p - 1], fb = kf[p];
      int   ia = ki[p - 1], ib = ki[p];
      bool sw = (fb < fa) || (fb == fa && ib < ia);
      kf[p - 1] = sw ? fb : fa; ki[p - 1] = sw ? ib : ia;
      kf[p]     = sw ? fa : fb; ki[p]     = sw ? ia : ib;
    }
  }
}

__device__ __forceinline__ unsigned short bf16_rn(float x) {
  unsigned int u = __float_as_uint(x);
  unsigned int r = u + 0x7fffu + ((u >> 16) & 1u);
  return (unsigned short)(r >> 16);
}

// ---------------------------------------------------------------- pack x
__global__ void pack_x_kernel(const float* __restrict__ x, float4* __restrict__ x4) {
  int i = blockIdx.x * blockDim.x + threadIdx.x;
  if (i < NPTS) {
    float a = x[3 * i], b = x[3 * i + 1], c = x[3 * i + 2];
    x4[i] = make_float4(a, b, c, a * a + b * b + c * c);
  }
}

// ---------------------------------------------------------------- Wc = [Wl-Wh | Wh] -> fragment-major bf16 hi/lo
__global__ void prep_w1f_kernel(const float* __restrict__ W1,
                                unsigned short* __restrict__ WcFhi,
                                unsigned short* __restrict__ WcFlo) {
  int idx = blockIdx.x * 256 + threadIdx.x;    // 128*512
  int k = idx >> 9, c = idx & 511;
  float wh = W1[(size_t)(HIDC + k) * OUTC2 + (c & 255)];
  float w = (c < OUTC2) ? (W1[(size_t)k * OUTC2 + c] - wh) : wh;
  unsigned short hi = bf16_rn(w);
  float fh = __uint_as_float(((unsigned int)hi) << 16);
  unsigned short lo = bf16_rn(w - fh);
  const int nt = c >> 4, ct = c & 15;
  const int s = k >> 5, kg = (k >> 3) & 3, e = k & 7;
  const size_t fidx = ((size_t)(s * 32 + nt) * 64 + (kg * 16 + ct)) * 8 + e;
  WcFhi[fidx] = hi;
  WcFlo[fidx] = lo;
}

// ---------------------------------------------------------------- W1b (128x128) -> fragment-major bf16 hi/lo
__global__ void prep_w1b_kernel(const float* __restrict__ W,
                                unsigned short* __restrict__ Fhi,
                                unsigned short* __restrict__ Flo) {
  const int c = blockIdx.x;
  const int k = threadIdx.x;
  float w = W[(size_t)k * HIDC + c];
  unsigned short hi = bf16_rn(w);
  float fh = __uint_as_float(((unsigned int)hi) << 16);
  unsigned short lo = bf16_rn(w - fh);
  const int nt = c >> 4, ct = c & 15;
  const int s = k >> 5, kg = (k >> 3) & 3, e = k & 7;
  const size_t idx = ((size_t)(s * 8 + nt) * 64 + (kg * 16 + ct)) * 8 + e;
  Fhi[idx] = hi;
  Flo[idx] = lo;
}

// ---------------------------------------------------------------- W2 (256x256) -> fragment-major bf16 hi/lo
__global__ void prep_w2_kernel(const float* __restrict__ W2,
                               unsigned short* __restrict__ W2Fhi,
                               unsigned short* __restrict__ W2Flo) {
  const int c = blockIdx.x;
  const int k = threadIdx.x;
  float w = W2[(size_t)k * OUTC2 + c];
  unsigned short hi = bf16_rn(w);
  float fh = __uint_as_float(((unsigned int)hi) << 16);
  unsigned short lo = bf16_rn(w - fh);
  const int nt = c >> 4, ct = c & 15;
  const int s  = k >> 5, kg = (k >> 3) & 3, e = k & 7;
  const int lane = kg * 16 + ct;
  const size_t idx = ((size_t)(s * 16 + nt) * 64 + lane) * 8 + e;
  W2Fhi[idx] = hi;
  W2Flo[idx] = lo;
}

// ---------------------------------------------------------------- KNN1 (C=3, K=16)
// Wave = 2 queries; lane processes 4 consecutive j per step (64B contiguous
// loads), sort4 + guarded bitonic top-8 update per query (exact set; keys
// unique so processing order is irrelevant). Then per-lane exact fp32
// rescore of its 8 + 16-pop heads-merge (R11-validated, duplicated x2).
__global__ __launch_bounds__(256) void knn3_kernel(const float4* __restrict__ X4,
                                                   int* __restrict__ idx_out) {
  const int tid  = threadIdx.x;
  const int lane = tid & 63;
  const int wv   = __builtin_amdgcn_readfirstlane(tid >> 6);
  const int qA   = blockIdx.x * 8 + wv * 2;
  const int qB   = qA + 1;

  const float4 qa = X4[qA];
  const float4 qb = X4[qB];

  unsigned kkA[KK2], kkB[KK2];
  #pragma unroll
  for (int k = 0; k < KK2; ++k) { kkA[k] = 0xFFFFFFFFu; kkB[k] = 0xFFFFFFFFu; }

  for (int c = 0; c < NPTS / 256; ++c) {
    const int j = c * 256 + lane * 4;
    float4 p[4];
    #pragma unroll
    for (int t = 0; t < 4; ++t) p[t] = X4[j + t];

    unsigned ka[4], kb[4];
    #pragma unroll
    for (int t = 0; t < 4; ++t) {
      float dA = fmaxf(qa.w + p[t].w - 2.f * (qa.x * p[t].x + qa.y * p[t].y + qa.z * p[t].z), 0.f);
      float dB = fmaxf(qb.w + p[t].w - 2.f * (qb.x * p[t].x + qb.y * p[t].y + qb.z * p[t].z), 0.f);
      ka[t] = (__float_as_uint(dA) & 0xFFFFE000u) | (unsigned)(j + t);
      kb[t] = (__float_as_uint(dB) & 0xFFFFE000u) | (unsigned)(j + t);
      if (j + t == qA) ka[t] = 0xFFFFFFFFu;
      if (j + t == qB) kb[t] = 0xFFFFFFFFu;
    }
    topk8_batch4(kkA, ka[0], ka[1], ka[2], ka[3]);
    topk8_batch4(kkB, kb[0], kb[1], kb[2], kb[3]);
  }

  // exact fp32 rescore of kept candidates, per query
  float kfA[KK2], kfB[KK2]; int kjA[KK2], kjB[KK2];
  #pragma unroll
  for (int k = 0; k < KK2; ++k) {
    kfA[k] = INFINITY; kjA[k] = 0x7fffffff;
    kfB[k] = INFINITY; kjB[k] = 0x7fffffff;
  }
  #pragma unroll
  for (int k = 0; k < KK2; ++k) {
    int j = (int)(kkA[k] & 0x1FFFu);
    float4 pj = X4[j];
    float d = qa.w + pj.w - 2.f * (qa.x * pj.x + qa.y * pj.y + qa.z * pj.z);
    if (kkA[k] == 0xFFFFFFFFu) { d = INFINITY; j = 0x7fffffff; }
    ins_lex<KK2>(kfA, kjA, d, j);
  }
  #pragma unroll
  for (int k = 0; k < KK2; ++k) {
    int j = (int)(kkB[k] & 0x1FFFu);
    float4 pj = X4[j];
    float d = qb.w + pj.w - 2.f * (qb.x * pj.x + qb.y * pj.y + qb.z * pj.z);
    if (kkB[k] == 0xFFFFFFFFu) { d = INFINITY; j = 0x7fffffff; }
    ins_lex<KK2>(kfB, kjB, d, j);
  }

  // heads-merge: 16 pops of wave-wide lex-argmin; query A then query B
  #pragma unroll
  for (int k = 0; k < KK1; ++k) {
    float mf = kfA[0]; int mj = kjA[0];
    #pragma unroll
    for (int m = 1; m <= 32; m <<= 1) {
      float of = __shfl_xor(mf, m, 64);
      int   oj = __shfl_xor(mj, m, 64);
      bool g = (of < mf) || (of == mf && oj < mj);
      mf = g ? of : mf; mj = g ? oj : mj;
    }
    const bool won = (kfA[0] == mf) && (kjA[0] == mj);
    if (won) {
      idx_out[(size_t)qA * KK1 + k] = mj;
      #pragma unroll
      for (int p = 0; p < KK2 - 1; ++p) { kfA[p] = kfA[p + 1]; kjA[p] = kjA[p + 1]; }
      kfA[KK2 - 1] = INFINITY; kjA[KK2 - 1] = 0x7fffffff;
    }
  }
  #pragma unroll
  for (int k = 0; k < KK1; ++k) {
    float mf = kfB[0]; int mj = kjB[0];
    #pragma unroll
    for (int m = 1; m <= 32; m <<= 1) {
      float of = __shfl_xor(mf, m, 64);
      int   oj = __shfl_xor(mj, m, 64);
      bool g = (of < mf) || (of == mf && oj < mj);
      mf = g ? of : mf; mj = g ? oj : mj;
    }
    const bool won = (kfB[0] == mf) && (kjB[0] == mj);
    if (won) {
      idx_out[(size_t)qB * KK1 + k] = mj;
      #pragma unroll
      for (int p = 0; p < KK2 - 1; ++p) { kfB[p] = kfB[p + 1]; kjB[p] = kjB[p + 1]; }
      kfB[KK2 - 1] = INFINITY; kjB[KK2 - 1] = 0x7fffffff;
    }
  }
}

// ---------------------------------------------------------------- EdgeConv 1 — MFMA stage-2 (R16-validated)
__global__ __launch_bounds__(512) void edgeconv1_kernel(
    const float* __restrict__ X, const int* __restrict__ knn,
    const float* __restrict__ W1, const float* __restrict__ b1,
    const unsigned short* __restrict__ W1bFhi, const unsigned short* __restrict__ W1bFlo,
    const float* __restrict__ b2,
    float* __restrict__ H, unsigned short* __restrict__ Hhi,
    unsigned short* __restrict__ Hlo, float* __restrict__ SQ2) {
  __shared__ __align__(16) unsigned short Ghi[128 * HIDC];
  __shared__ __align__(16) unsigned short Glo[128 * HIDC];
  __shared__ __align__(16) unsigned short Bs[2][2][4096];
  __shared__ float xjs[8][KK1][3];
  __shared__ float xis[8][3];
  const int tid  = threadIdx.x;
  const int lane = tid & 63;
  const int wv   = __builtin_amdgcn_readfirstlane(tid >> 6);
  const int p    = blockIdx.x * 8 + wv;

  if (lane < KK1) {
    int j = knn[p * KK1 + lane];
    xjs[wv][lane][0] = X[3 * j]; xjs[wv][lane][1] = X[3 * j + 1]; xjs[wv][lane][2] = X[3 * j + 2];
  } else if (lane < KK1 + 3) {
    xis[wv][lane - KK1] = X[3 * p + lane - KK1];
  }
  __syncthreads();

  {
    const int ch0 = lane * 2;
    float2 w1r[6];
    #pragma unroll
    for (int c = 0; c < 6; ++c)
      w1r[c] = make_float2(W1[c * HIDC + ch0], W1[c * HIDC + ch0 + 1]);
    const float2 b1v = make_float2(b1[ch0], b1[ch0 + 1]);
    const float xi0 = xis[wv][0], xi1 = xis[wv][1], xi2 = xis[wv][2];
    const float base0 = b1v.x + xi0 * w1r[0].x + xi1 * w1r[1].x + xi2 * w1r[2].x;
    const float base1 = b1v.y + xi0 * w1r[0].y + xi1 * w1r[1].y + xi2 * w1r[2].y;
    #pragma unroll
    for (int e = 0; e < KK1; ++e) {
      float dx = xjs[wv][e][0] - xi0, dy = xjs[wv][e][1] - xi1, dz = xjs[wv][e][2] - xi2;
      float v0 = fmaxf(base0 + dx * w1r[3].x + dy * w1r[4].x + dz * w1r[5].x, 0.f);
      float v1 = fmaxf(base1 + dx * w1r[3].y + dy * w1r[4].y + dz * w1r[5].y, 0.f);
      unsigned short h0 = bf16_rn(v0), h1s = bf16_rn(v1);
      unsigned short l0 = bf16_rn(v0 - __uint_as_float(((unsigned)h0) << 16));
      unsigned short l1 = bf16_rn(v1 - __uint_as_float(((unsigned)h1s) << 16));
      const int r   = wv * 16 + e;
      const int off = r * 256 + (((ch0 >> 3) ^ (r & 7)) << 4) + ((ch0 & 7) << 1);
      *(ushort2*)((char*)Ghi + off) = make_ushort2(h0, h1s);
      *(ushort2*)((char*)Glo + off) = make_ushort2(l0, l1);
    }
  }

  auto stageB = [&](int buf, int s) {
    const size_t go = (size_t)s * 4096 + (size_t)wv * 512 + (size_t)lane * 8;
    async_ld16((char*)&Bs[buf][0][0] + wv * 1024, W1bFhi + go);
    async_ld16((char*)&Bs[buf][1][0] + wv * 1024, W1bFlo + go);
  };

  stageB(0, 0);
  asm volatile("s_waitcnt vmcnt(0)" ::: "memory");
  __syncthreads();

  const int col = lane & 15;
  const int kg  = lane >> 4;
  const int ar  = wv * 16 + col;
  const int abase = ar * 256;

  f32x4 acc[8];
  #pragma unroll
  for (int n = 0; n < 8; ++n) acc[n] = (f32x4){0.f, 0.f, 0.f, 0.f};

  for (int s = 0; s < 4; ++s) {
    const int cur = s & 1;
    if (s + 1 < 4) stageB(cur ^ 1, s + 1);
    const int asl = (((s * 4 + kg) ^ (ar & 7)) << 4);
    short8 ghi = *(const short8*)((const char*)Ghi + abase + asl);
    short8 glo = *(const short8*)((const char*)Glo + abase + asl);
    #pragma unroll
    for (int n = 0; n < 8; ++n) {
      const int bo = (n * 64 + lane) * 16;
      short8 bhi = *(const short8*)((const char*)&Bs[cur][0][0] + bo);
      short8 blo = *(const short8*)((const char*)&Bs[cur][1][0] + bo);
      acc[n] = mfma16(ghi, bhi, acc[n]);
      acc[n] = mfma16(ghi, blo, acc[n]);
      acc[n] = mfma16(glo, bhi, acc[n]);
    }
    asm volatile("s_waitcnt vmcnt(0)" ::: "memory");
    __syncthreads();
  }

  float sq = 0.f;
  float hv[8];
  #pragma unroll
  for (int n = 0; n < 8; ++n) {
    float m = fmaxf(fmaxf(acc[n][0], acc[n][1]), fmaxf(acc[n][2], acc[n][3]));
    m = fmaxf(m, __shfl_xor(m, 16, 64));
    m = fmaxf(m, __shfl_xor(m, 32, 64));
    m += b2[n * 16 + col];
    hv[n] = m;
    sq += m * m;
  }
  if (kg == 0) {
    #pragma unroll
    for (int n = 0; n < 8; ++n) {
      const int ch = n * 16 + col;
      H[(size_t)p * HIDC + ch] = hv[n];
      unsigned short hb = bf16_rn(hv[n]);
      float fh = __uint_as_float(((unsigned)hb) << 16);
      Hhi[(size_t)p * HIDC + ch] = hb;
      Hlo[(size_t)p * HIDC + ch] = bf16_rn(hv[n] - fh);
    }
  }
  #pragma unroll
  for (int m2 = 1; m2 <= 8; m2 <<= 1) sq += __shfl_xor(sq, m2, 64);
  if (lane == 0) SQ2[p] = sq;
}

// ---------------------------------------------------------------- PQ = H @ Wc via MFMA (R16-validated)
__global__ __launch_bounds__(512) void gemm_pq_kernel(
    const unsigned short* __restrict__ Hhi, const unsigned short* __restrict__ Hlo,
    const unsigned short* __restrict__ WcFhi, const unsigned short* __restrict__ WcFlo,
    const float* __restrict__ b1, float* __restrict__ PQ) {
  __shared__ __align__(16) unsigned short Ahi[64 * HIDC];
  __shared__ __align__(16) unsigned short Alo[64 * HIDC];
  __shared__ __align__(16) unsigned short Bsl[2][2][8192];
  const int tid  = threadIdx.x;
  const int lane = tid & 63;
  const int wv   = __builtin_amdgcn_readfirstlane(tid >> 6);
  const int mb   = blockIdx.x >> 1;
  const int ns   = blockIdx.x & 1;
  const int r0   = mb * 64;

  #pragma unroll
  for (int i = 0; i < 2; ++i) {
    const int srow = wv * 8 + i * 4 + (lane >> 4);
    const int sslt = (lane & 15) ^ (srow & 7);
    const size_t go = (size_t)(r0 + srow) * HIDC + sslt * 8;
    async_ld16((char*)Ahi + (wv * 8 + i * 4) * 256, Hhi + go);
    async_ld16((char*)Alo + (wv * 8 + i * 4) * 256, Hlo + go);
  }
  auto stageB = [&](int buf, int s) {
    #pragma unroll
    for (int i = 0; i < 2; ++i) {
      const size_t go = (size_t)(s * 32 + ns * 16) * 512 + (size_t)wv * 1024 + i * 512 + lane * 8;
      async_ld16((char*)&Bsl[buf][0][0] + wv * 2048 + i * 1024, WcFhi + go);
      async_ld16((char*)&Bsl[buf][1][0] + wv * 2048 + i * 1024, WcFlo + go);
    }
  };
  stageB(0, 0);
  asm volatile("s_waitcnt vmcnt(0)" ::: "memory");
  __syncthreads();

  const int col = lane & 15;
  const int kg  = lane >> 4;
  const int mt  = wv & 3;
  const int nh  = wv >> 2;
  const int ar  = mt * 16 + col;
  const int abase = ar * 256;

  f32x4 acc[8];
  #pragma unroll
  for (int n = 0; n < 8; ++n) acc[n] = (f32x4){0.f, 0.f, 0.f, 0.f};

  for (int s = 0; s < 4; ++s) {
    const int cur = s & 1;
    if (s + 1 < 4) stageB(cur ^ 1, s + 1);
    const int asl = (((s * 4 + kg) ^ (ar & 7)) << 4);
    short8 ahi8 = *(const short8*)((const char*)Ahi + abase + asl);
    short8 alo8 = *(const short8*)((const char*)Alo + abase + asl);
    #pragma unroll
    for (int n = 0; n < 8; ++n) {
      const int ntl = nh * 8 + n;
      const int bo = (ntl * 64 + lane) * 16;
      short8 bhi = *(const short8*)((const char*)&Bsl[cur][0][0] + bo);
      short8 blo = *(const short8*)((const char*)&Bsl[cur][1][0] + bo);
      acc[n] = mfma16(ahi8, bhi, acc[n]);
      acc[n] = mfma16(ahi8, blo, acc[n]);
      acc[n] = mfma16(alo8, bhi, acc[n]);
    }
    asm volatile("s_waitcnt vmcnt(0)" ::: "memory");
    __syncthreads();
  }

  #pragma unroll
  for (int n = 0; n < 8; ++n) {
    const int cg = ns * 256 + (nh * 8 + n) * 16 + col;
    const float bb = (ns == 0) ? b1[cg] : 0.f;
    #pragma unroll
    for (int r = 0; r < 4; ++r) {
      const int row = r0 + mt * 16 + kg * 4 + r;
      PQ[(size_t)row * PQC + cg] = acc[n][r] + bb;
    }
  }
}

// ---------------------------------------------------------------- KNN2 filter (bitonic batch selection)
constexpr int JSPLIT = 16;
constexpr int JPB2   = NPTS / JSPLIT;
constexpr int NCH    = JPB2 / 16;
constexpr int CPQ    = JSPLIT * KK2;   // 128 keys per query

__global__ __launch_bounds__(256) void knn128_filter_kernel(
    const unsigned short* __restrict__ Hhi, const unsigned short* __restrict__ Hlo,
    const float* __restrict__ SQ, unsigned* __restrict__ pk2) {
  __shared__ __align__(16) unsigned short As[2][2][16 * HIDC];
  const int tid  = threadIdx.x;
  const int lane = tid & 63;
  const int wv   = __builtin_amdgcn_readfirstlane(tid >> 6);
  const int qb   = blockIdx.x >> 4;
  const int js   = blockIdx.x & 15;
  const int col  = lane & 15;
  const int kg   = lane >> 4;
  const int qg   = qb * 64 + wv * 16 + col;

  short8 qhi[4], qlo[4];
  #pragma unroll
  for (int s = 0; s < 4; ++s) {
    const size_t o = (size_t)qg * HIDC + s * 32 + kg * 8;
    qhi[s] = *reinterpret_cast<const short8*>(Hhi + o);
    qlo[s] = *reinterpret_cast<const short8*>(Hlo + o);
  }
  const float sqq = SQ[qg];

  unsigned kk[KK2];
  #pragma unroll
  for (int k = 0; k < KK2; ++k) kk[k] = 0xFFFFFFFFu;

  const int jbase = js * JPB2;

  const int srow = 4 * wv + (lane >> 4);
  const int sslt = (lane & 15) ^ (srow & 7);
  auto stage = [&](int buf, int ch) {
    const size_t gofs = (size_t)(jbase + ch * 16 + srow) * HIDC + sslt * 8;
    async_ld16((char*)&As[buf][0][0] + wv * 1024, Hhi + gofs);
    async_ld16((char*)&As[buf][1][0] + wv * 1024, Hlo + gofs);
  };

  stage(0, 0);
  asm volatile("s_waitcnt vmcnt(0)" ::: "memory");
  __syncthreads();

  for (int ch = 0; ch < NCH; ++ch) {
    const int cur = ch & 1;
    if (ch + 1 < NCH) stage(cur ^ 1, ch + 1);

    const int jb = jbase + ch * 16;
    short8 ahi[4], alo[4];
    const int rowb = col * 256;
    #pragma unroll
    for (int s = 0; s < 4; ++s) {
      const int sl = ((s * 4 + kg) ^ (col & 7)) * 16;
      ahi[s] = *(const short8*)((const char*)&As[cur][0][0] + rowb + sl);
      alo[s] = *(const short8*)((const char*)&As[cur][1][0] + rowb + sl);
    }
    f32x4 sqjv = *reinterpret_cast<const f32x4*>(SQ + jb + kg * 4);

    f32x4 acc = {0.f, 0.f, 0.f, 0.f};
    #pragma unroll
    for (int s = 0; s < 4; ++s) {
      acc = mfma16(ahi[s], qhi[s], acc);
      acc = mfma16(ahi[s], qlo[s], acc);
      acc = mfma16(alo[s], qhi[s], acc);
    }
    unsigned kb[4];
    #pragma unroll
    for (int r = 0; r < 4; ++r) {
      const int jg = jb + kg * 4 + r;
      float d = fmaxf(sqq + sqjv[r] - 2.f * acc[r], 0.f);
      kb[r] = (__float_as_uint(d) & 0xFFFFE000u) | (unsigned)jg;
      if (jg == qg) kb[r] = 0xFFFFFFFFu;
    }
    topk8_batch4(kk, kb[0], kb[1], kb[2], kb[3]);
    asm volatile("s_waitcnt vmcnt(0)" ::: "memory");
    __syncthreads();
  }

  // merge 4 kgroup lists (same query at lanes ^16, ^32) -> top-8 of split.
  // Each incoming list is sorted asc; feed as two batches of 4.
  #pragma unroll
  for (int dlt = 16; dlt <= 32; dlt <<= 1) {
    unsigned ok[KK2];
    #pragma unroll
    for (int k = 0; k < KK2; ++k) ok[k] = __shfl_xor((int)kk[k], dlt, 64);
    topk8_batch4(kk, ok[0], ok[1], ok[2], ok[3]);
    topk8_batch4(kk, ok[4], ok[5], ok[6], ok[7]);
  }
  if (lane < 16) {
    const size_t base = (size_t)qg * CPQ + js * KK2;
    #pragma unroll
    for (int k = 0; k < KK2; ++k) pk2[base + k] = kk[k];
  }
}

// ---------------------------------------------------------------- rescore (unchanged from R15)
__global__ __launch_bounds__(256) void knn_rescore_kernel(
    const float* __restrict__ H, const float* __restrict__ SQ,
    const unsigned* __restrict__ pk2, int* __restrict__ idx_out) {
  __shared__ float qrow[16][HIDC + 4];
  const int tid  = threadIdx.x;
  const int lane = tid & 63;
  const int wv   = tid >> 6;
  const int g    = lane >> 4;
  const int sl   = lane & 15;
  const int q0   = blockIdx.x * 16;
  const int qloc = wv * 4 + g;
  const int q    = q0 + qloc;

  for (int u = tid; u < 16 * 32; u += 256) {
    int r = u >> 5, c4 = u & 31;
    *(f32x4*)&qrow[r][c4 * 4] = *(const f32x4*)&H[(size_t)(q0 + r) * HIDC + c4 * 4];
  }
  __syncthreads();

  unsigned kreg[KK2];
  {
    const unsigned* src = pk2 + (size_t)q * CPQ + sl * KK2;
    uint4 a = *(const uint4*)(src);
    uint4 b = *(const uint4*)(src + 4);
    kreg[0] = a.x; kreg[1] = a.y; kreg[2] = a.z; kreg[3] = a.w;
    kreg[4] = b.x; kreg[5] = b.y; kreg[6] = b.z; kreg[7] = b.w;
  }

  unsigned ckey = 0xFFFFFFFFu;
  #pragma unroll
  for (int t = 0; t < 16; ++t) {
    unsigned m = kreg[0];
    #pragma unroll
    for (int mm = 1; mm <= 8; mm <<= 1) {
      unsigned o = (unsigned)__shfl_xor((int)m, mm, 64);
      m = o < m ? o : m;
    }
    if (t == sl) ckey = m;
    const bool won = (kreg[0] == m);
    if (won) {
      #pragma unroll
      for (int p = 0; p < KK2 - 1; ++p) kreg[p] = kreg[p + 1];
      kreg[KK2 - 1] = 0xFFFFFFFFu;
    }
  }
  const int ci = (int)(ckey & 0x1FFFu);

  const float* crow = H + (size_t)ci * HIDC;
  float dot = 0.f;
  #pragma unroll 8
  for (int c4 = 0; c4 < HIDC / 4; ++c4) {
    f32x4 qv = *(const f32x4*)&qrow[qloc][c4 * 4];
    f32x4 cv = *(const f32x4*)(crow + c4 * 4);
    dot += qv[0] * cv[0] + qv[1] * cv[1] + qv[2] * cv[2] + qv[3] * cv[3];
  }
  float d = SQ[q] + SQ[ci] - 2.f * dot;

  float kf[KK2]; int ki[KK2];
  kf[0] = d; ki[0] = ci;
  #pragma unroll
  for (int k = 1; k < KK2; ++k) { kf[k] = INFINITY; ki[k] = 0x7fffffff; }
  #pragma unroll
  for (int dlt = 1; dlt <= 8; dlt <<= 1) {
    float of[KK2]; int oi[KK2];
    #pragma unroll
    for (int k = 0; k < KK2; ++k) { of[k] = __shfl_xor(kf[k], dlt, 64); oi[k] = __shfl_xor(ki[k], dlt, 64); }
    #pragma unroll
    for (int k = 0; k < KK2; ++k) ins_lex<KK2>(kf, ki, of[k], oi[k]);
  }
  if (sl == 0) {
    #pragma unroll
    for (int k = 0; k < KK2; ++k) idx_out[(size_t)q * KK2 + k] = ki[k];
  }
}

// ---------------------------------------------------------------- EdgeConv 2 — MFMA, LDS-staged B (R14-validated)
__global__ __launch_bounds__(512) void edgeconv2_kernel(
    const float* __restrict__ PQ, const int* __restrict__ knn,
    const unsigned short* __restrict__ W2Fhi, const unsigned short* __restrict__ W2Flo,
    const float* __restrict__ b2, float* __restrict__ Out) {
  __shared__ __align__(16) unsigned short Ghi[64 * OUTC2];
  __shared__ __align__(16) unsigned short Glo[64 * OUTC2];
  __shared__ __align__(16) unsigned short Bs[2][2][8192];
  const int tid  = threadIdx.x;
  const int lane = tid & 63;
  const int wv   = __builtin_amdgcn_readfirstlane(tid >> 6);
  const int p_base = blockIdx.x * 8;

  {
    const int p   = p_base + wv;
    const int ch0 = lane * 4;
    f32x4 pv = *(const f32x4*)&PQ[(size_t)p * PQC + ch0];
    #pragma unroll
    for (int e = 0; e < KK2; ++e) {
      const int j = knn[p * KK2 + e];
      f32x4 qv = *(const f32x4*)&PQ[(size_t)j * PQC + OUTC2 + ch0];
      unsigned short hb[4], lb[4];
      #pragma unroll
      for (int c = 0; c < 4; ++c) {
        float g = fmaxf(pv[c] + qv[c], 0.f);
        hb[c] = bf16_rn(g);
        float fh = __uint_as_float(((unsigned int)hb[c]) << 16);
        lb[c] = bf16_rn(g - fh);
      }
      const int r   = wv * 8 + e;
      const int off = r * 512 + (((ch0 >> 3) ^ (r & 7)) << 4) + ((ch0 & 7) << 1);
      *(ushort4*)((char*)Ghi + off) = make_ushort4(hb[0], hb[1], hb[2], hb[3]);
      *(ushort4*)((char*)Glo + off) = make_ushort4(lb[0], lb[1], lb[2], lb[3]);
    }
  }

  auto stageB = [&](int buf, int s) {
    #pragma unroll
    for (int i = 0; i < 2; ++i) {
      const size_t go = (size_t)s * 8192 + (size_t)(wv * 2 + i) * 512 + (size_t)lane * 8;
      async_ld16((char*)&Bs[buf][0][0] + (wv * 2 + i) * 1024, W2Fhi + go);
      async_ld16((char*)&Bs[buf][1][0] + (wv * 2 + i) * 1024, W2Flo + go);
    }
  };

  stageB(0, 0);
  asm volatile("s_waitcnt vmcnt(0)" ::: "memory");
  __syncthreads();

  const int col = lane & 15;
  const int kg  = lane >> 4;
  const int mt  = wv & 3;
  const int nh  = wv >> 2;
  const int ar  = mt * 16 + col;
  const int abase = ar * 512;

  f32x4 acc[8];
  #pragma unroll
  for (int n = 0; n < 8; ++n) acc[n] = (f32x4){0.f, 0.f, 0.f, 0.f};

  for (int s = 0; s < 8; ++s) {
    const int cur = s & 1;
    if (s + 1 < 8) stageB(cur ^ 1, s + 1);

    const int asl = (((s * 4 + kg) ^ (ar & 7)) << 4);
    short8 ghi = *(const short8*)((const char*)Ghi + abase + asl);
    short8 glo = *(const short8*)((const char*)Glo + abase + asl);
    #pragma unroll
    for (int n = 0; n < 8; ++n) {
      const int nt = nh * 8 + n;
      const int bo = (nt * 64 + lane) * 16;
      short8 bhi = *(const short8*)((const char*)&Bs[cur][0][0] + bo);
      short8 blo = *(const short8*)((const char*)&Bs[cur][1][0] + bo);
      acc[n] = mfma16(ghi, bhi, acc[n]);
      acc[n] = mfma16(ghi, blo, acc[n]);
      acc[n] = mfma16(glo, bhi, acc[n]);
    }
    asm volatile("s_waitcnt vmcnt(0)" ::: "memory");
    __syncthreads();
  }

  const int pt = p_base + mt * 2 + (kg >> 1);
  #pragma unroll
  for (int n = 0; n < 8; ++n) {
    float m = fmaxf(fmaxf(acc[n][0], acc[n][1]), fmaxf(acc[n][2], acc[n][3]));
    m = fmaxf(m, __shfl_xor(m, 16, 64));
    if ((kg & 1) == 0) {
      const int ncol = nh * 128 + n * 16 + col;
      Out[(size_t)pt * OUTC2 + ncol] = m + b2[ncol];
    }
  }
}

// ---------------------------------------------------------------- launch
extern "C" void kernel_launch(void* const* d_in, const int* in_sizes, int n_in,
                              void* d_out, int out_size, void* d_ws, size_t ws_size,
                              hipStream_t stream) {
  const float* x   = (const float*)d_in[0];
  const float* W1a = (const float*)d_in[1];
  const float* b1a = (const float*)d_in[2];
  const float* W1b = (const float*)d_in[3];
  const float* b1b = (const float*)d_in[4];
  const float* W2a = (const float*)d_in[5];
  const float* b2a = (const float*)d_in[6];
  const float* W2b = (const float*)d_in[7];
  const float* b2b = (const float*)d_in[8];
  float* out = (float*)d_out;

  float* h    = (float*)d_ws;                       // 4 MB
  float* sq2  = h + (size_t)NPTS * HIDC;
  int*   idx1 = (int*)(sq2 + NPTS);
  int*   idx2 = idx1 + (size_t)NPTS * KK1;
  unsigned short* Hhi = (unsigned short*)(idx2 + (size_t)NPTS * KK2);  // 2 MB
  unsigned short* Hlo = Hhi + (size_t)NPTS * HIDC;                     // 2 MB
  unsigned* pk2 = (unsigned*)(Hlo + (size_t)NPTS * HIDC);              // 4 MB
  float* PQ   = (float*)(pk2 + (size_t)NPTS * CPQ); // 16 MB
  unsigned short* W2Fhi = (unsigned short*)(PQ + (size_t)NPTS * PQC);  // 128 KB
  unsigned short* W2Flo = W2Fhi + (size_t)OUTC2 * OUTC2;               // 128 KB
  unsigned short* WcFhi = W2Flo + (size_t)OUTC2 * OUTC2;               // 128 KB
  unsigned short* WcFlo = WcFhi + (size_t)HIDC * PQC;                  // 128 KB
  unsigned short* W1bFhi = WcFlo + (size_t)HIDC * PQC;                 // 32 KB
  unsigned short* W1bFlo = W1bFhi + (size_t)HIDC * HIDC;               // 32 KB
  // x4 aliases h's first 128KB: knn3 finishes before edgeconv1 writes h.
  float4* x4 = (float4*)h;

  pack_x_kernel<<<(NPTS + 255) / 256, 256, 0, stream>>>(x, x4);
  prep_w1f_kernel<<<(HIDC * PQC) / 256, 256, 0, stream>>>(W2a, WcFhi, WcFlo);
  prep_w1b_kernel<<<HIDC, HIDC, 0, stream>>>(W1b, W1bFhi, W1bFlo);
  prep_w2_kernel<<<OUTC2, OUTC2, 0, stream>>>(W2b, W2Fhi, W2Flo);
  knn3_kernel<<<NPTS / 8, 256, 0, stream>>>(x4, idx1);
  edgeconv1_kernel<<<NPTS / 8, 512, 0, stream>>>(x, idx1, W1a, b1a,
                                                 W1bFhi, W1bFlo, b1b,
                                                 h, Hhi, Hlo, sq2);
  gemm_pq_kernel<<<(NPTS / 64) * 2, 512, 0, stream>>>(Hhi, Hlo, WcFhi, WcFlo, b2a, PQ);
  knn128_filter_kernel<<<(NPTS / 64) * JSPLIT, 256, 0, stream>>>(Hhi, Hlo, sq2, pk2);
  knn_rescore_kernel<<<NPTS / 16, 256, 0, stream>>>(h, sq2, pk2, idx2);
  edgeconv2_kernel<<<NPTS / 8, 512, 0, stream>>>(PQ, idx2, W2Fhi, W2Flo, b2b, out);
}